// Round 15
// baseline (128.004 us; speedup 1.0000x reference)
//
#include <hip/hip_runtime.h>
#include <hip/hip_bf16.h>

#define IN_DIM 128
#define HID    64
#define OUTD   64
#define NPART  8
#define SUBW   64            // nodes per level-2 window (power of 2)
#define SUBSH  23            // pk >> SUBSH = sub index (17 + log2(SUBW))
#define CAP    1536          // sorted-edge capacity (mean 1020, sigma 32: +16 sigma)
#define MAXNSUB 200
#define PROJ_BLOCKS 1043
#define BKT_BLOCKS 1024      // level-1 radix: NW = 4096 waves
#define L2_BLOCKS 512        // level-2: 256 waves per partition

typedef __attribute__((ext_vector_type(8))) short bf16x8;
typedef __attribute__((ext_vector_type(4))) float f32x4;

__device__ __forceinline__ float gelu_exact(float v) {
    return v * 0.5f * (1.0f + erff(v * 0.70710678118654752f));
}
__device__ __forceinline__ short f2bf(float f) {
    __hip_bfloat16 b = __float2bfloat16(f);   // RNE
    return *reinterpret_cast<short*>(&b);
}
__device__ __forceinline__ float bf2f(ushort u) {
    return __uint_as_float(((unsigned)u) << 16);
}

// ---------------------------------------------------------------------------
// FUSED K1: blocks [0,PROJ_BLOCKS) = MFMA node projection; rest = level-1
// count (ballot, no atomics). Independent -> concurrent.
// ---------------------------------------------------------------------------
__global__ __launch_bounds__(256) void k_proj_bcount(
    const float* __restrict__ x, const float* __restrict__ w_in,
    const float* __restrict__ b_in, const float* __restrict__ w,
    const float* __restrict__ a,
    ushort* __restrict__ zb, float* __restrict__ s1, float* __restrict__ s2,
    const int* __restrict__ dst, int* __restrict__ wcnt,
    int n_nodes, int ntiles, int n_edges, int part_sz)
{
    __shared__ ushort h0s[4][16 * 64];

    const int tid = threadIdx.x;

    if (blockIdx.x < PROJ_BLOCKS) {
        const int wv = tid >> 6, l = tid & 63;
        const int c = l & 15, g = l >> 4;

        bf16x8 B1[4][4];
        #pragma unroll
        for (int s = 0; s < 4; ++s)
            #pragma unroll
            for (int t = 0; t < 4; ++t) {
                bf16x8 f;
                #pragma unroll
                for (int e = 0; e < 8; ++e)
                    f[e] = f2bf(w_in[(s * 32 + g * 8 + e) * HID + t * 16 + c]);
                B1[s][t] = f;
            }
        bf16x8 B2[2][4];
        #pragma unroll
        for (int s = 0; s < 2; ++s)
            #pragma unroll
            for (int t = 0; t < 4; ++t) {
                bf16x8 f;
                #pragma unroll
                for (int e = 0; e < 8; ++e)
                    f[e] = f2bf(w[(s * 32 + g * 8 + e) * OUTD + t * 16 + c]);
                B2[s][t] = f;
            }
        float bias[4], a1c[4], a2c[4];
        #pragma unroll
        for (int t = 0; t < 4; ++t) {
            bias[t] = b_in[t * 16 + c];
            a1c[t]  = a[t * 16 + c];
            a2c[t]  = a[OUTD + t * 16 + c];
        }

        ushort* hrow = &h0s[wv][0];

        for (int tile = blockIdx.x; tile < ntiles; tile += PROJ_BLOCKS) {
            const int nbase = tile * 64 + wv * 16;

            const int row = min(nbase + c, n_nodes - 1);
            const float* xp = x + (size_t)row * IN_DIM;
            bf16x8 A1[4];
            #pragma unroll
            for (int s = 0; s < 4; ++s) {
                const float4 u0 = *(const float4*)(xp + s * 32 + g * 8);
                const float4 u1 = *(const float4*)(xp + s * 32 + g * 8 + 4);
                bf16x8 f;
                f[0] = f2bf(u0.x); f[1] = f2bf(u0.y); f[2] = f2bf(u0.z); f[3] = f2bf(u0.w);
                f[4] = f2bf(u1.x); f[5] = f2bf(u1.y); f[6] = f2bf(u1.z); f[7] = f2bf(u1.w);
                A1[s] = f;
            }

            #pragma unroll
            for (int t = 0; t < 4; ++t) {
                f32x4 acc = {0.f, 0.f, 0.f, 0.f};
                #pragma unroll
                for (int s = 0; s < 4; ++s)
                    acc = __builtin_amdgcn_mfma_f32_16x16x32_bf16(A1[s], B1[s][t], acc, 0, 0, 0);
                #pragma unroll
                for (int r = 0; r < 4; ++r) {
                    const int m = g * 4 + r;
                    const int n = t * 16 + c;
                    const float h0 = gelu_exact(acc[r] + bias[t]);
                    hrow[m * 64 + (n ^ ((m & 7) << 3))] = (ushort)f2bf(h0);
                }
            }
            __syncthreads();

            bf16x8 A2[2];
            #pragma unroll
            for (int s = 0; s < 2; ++s) {
                const int k = s * 32 + g * 8;
                A2[s] = *(const bf16x8*)(hrow + c * 64 + (k ^ ((c & 7) << 3)));
            }

            f32x4 C2[4];
            #pragma unroll
            for (int t = 0; t < 4; ++t) {
                f32x4 acc = {0.f, 0.f, 0.f, 0.f};
                acc = __builtin_amdgcn_mfma_f32_16x16x32_bf16(A2[0], B2[0][t], acc, 0, 0, 0);
                acc = __builtin_amdgcn_mfma_f32_16x16x32_bf16(A2[1], B2[1][t], acc, 0, 0, 0);
                C2[t] = acc;
            }

            float p1v[4] = {0.f, 0.f, 0.f, 0.f}, p2v[4] = {0.f, 0.f, 0.f, 0.f};
            #pragma unroll
            for (int t = 0; t < 4; ++t)
                #pragma unroll
                for (int r = 0; r < 4; ++r) {
                    p1v[r] = fmaf(C2[t][r], a1c[t], p1v[r]);
                    p2v[r] = fmaf(C2[t][r], a2c[t], p2v[r]);
                    const int node = nbase + g * 4 + r;
                    if (node < n_nodes)
                        zb[(size_t)node * OUTD + t * 16 + c] = (ushort)f2bf(C2[t][r]);
                }

            #pragma unroll
            for (int r = 0; r < 4; ++r) {
                p1v[r] += __shfl_xor(p1v[r], 1, 64);
                p1v[r] += __shfl_xor(p1v[r], 2, 64);
                p1v[r] += __shfl_xor(p1v[r], 4, 64);
                p1v[r] += __shfl_xor(p1v[r], 8, 64);
                p2v[r] += __shfl_xor(p2v[r], 1, 64);
                p2v[r] += __shfl_xor(p2v[r], 2, 64);
                p2v[r] += __shfl_xor(p2v[r], 4, 64);
                p2v[r] += __shfl_xor(p2v[r], 8, 64);
            }
            const float v1 = (c == 0) ? p1v[0] : (c == 1) ? p1v[1] : (c == 2) ? p1v[2] : p1v[3];
            const float v2 = (c == 0) ? p2v[0] : (c == 1) ? p2v[1] : (c == 2) ? p2v[2] : p2v[3];
            const int snode = nbase + g * 4 + c;
            if (c < 4 && snode < n_nodes) { s1[snode] = v1; s2[snode] = v2; }
            __syncthreads();
        }
    } else {
        const int bid = blockIdx.x - PROJ_BLOCKS;
        const int lane = tid & 63;
        const int gw = (bid * 256 + tid) >> 6;
        const int nw = (BKT_BLOCKS * 256) >> 6;

        int cnt[NPART];
        #pragma unroll
        for (int p = 0; p < NPART; ++p) cnt[p] = 0;

        const int tiles = (n_edges + 255) >> 8;
        for (int t = gw; t < tiles; t += nw) {
            const int base = (t << 8) + (lane << 2);
            int p0 = -1, p1 = -1, p2 = -1, p3 = -1;
            if (base + 3 < n_edges) {
                const int4 d4 = *(const int4*)(dst + base);
                p0 = d4.x / part_sz; p1 = d4.y / part_sz;
                p2 = d4.z / part_sz; p3 = d4.w / part_sz;
            } else {
                if (base + 0 < n_edges) p0 = dst[base + 0] / part_sz;
                if (base + 1 < n_edges) p1 = dst[base + 1] / part_sz;
                if (base + 2 < n_edges) p2 = dst[base + 2] / part_sz;
                if (base + 3 < n_edges) p3 = dst[base + 3] / part_sz;
            }
            #pragma unroll
            for (int pp = 0; pp < NPART; ++pp) {
                cnt[pp] += __popcll(__ballot(p0 == pp)) + __popcll(__ballot(p1 == pp))
                         + __popcll(__ballot(p2 == pp)) + __popcll(__ballot(p3 == pp));
            }
        }
        if (lane == 0) {
            #pragma unroll
            for (int pp = 0; pp < NPART; ++pp) wcnt[pp * nw + gw] = cnt[pp];
        }
    }
}

// ---------------------------------------------------------------------------
// Level-1 scan (merged wtot+wscan, SEGMENTED: thread t owns a contiguous
// segment -> serial sum -> one 256-wide block scan -> serial prefix write).
// Each of 8 blocks computes all partition sums itself (trivial).
// ---------------------------------------------------------------------------
__global__ __launch_bounds__(256) void k_wscan(
    int* __restrict__ wcnt, int* __restrict__ tot8,
    int* __restrict__ off8, int nw)
{
    __shared__ int buf[256];
    __shared__ int sums[NPART];
    const int p = blockIdx.x, tid = threadIdx.x;
    const int seg = (nw + 255) >> 8;
    const int s0 = tid * seg, s1e = min(s0 + seg, nw);

    // all 8 partition sums (for off8 base)
    for (int q = 0; q < NPART; ++q) {
        int s = 0;
        for (int i = s0; i < s1e; ++i) s += wcnt[q * nw + i];
        buf[tid] = s;
        __syncthreads();
        #pragma unroll
        for (int off = 128; off; off >>= 1) {
            if (tid < off) buf[tid] += buf[tid + off];
            __syncthreads();
        }
        if (tid == 0) sums[q] = buf[0];
        __syncthreads();
    }
    if (tid == 0) {
        tot8[p] = sums[p];
        if (p == 0) {
            int a = 0;
            for (int q = 0; q < NPART; ++q) { off8[q] = a; a += sums[q]; }
        }
    }
    int running = 0;
    for (int q = 0; q < p; ++q) running += sums[q];

    int tsum = 0;
    for (int i = s0; i < s1e; ++i) tsum += wcnt[p * nw + i];
    buf[tid] = tsum;
    __syncthreads();
    #pragma unroll
    for (int off = 1; off < 256; off <<= 1) {
        int t = (tid >= off) ? buf[tid - off] : 0;
        __syncthreads();
        buf[tid] += t;
        __syncthreads();
    }
    int prefix = running + buf[tid] - tsum;
    for (int i = s0; i < s1e; ++i) {
        const int v = wcnt[p * nw + i];
        wcnt[p * nw + i] = prefix;
        prefix += v;
    }
}

__global__ __launch_bounds__(256) void k_bwrite(
    const int* __restrict__ src, const int* __restrict__ dst,
    const int* __restrict__ wbase, unsigned* __restrict__ bkt,
    int n_edges, int part_sz)
{
    const int lane = threadIdx.x & 63;
    const int gw = (blockIdx.x * 256 + threadIdx.x) >> 6;
    const int nw = (gridDim.x * 256) >> 6;
    const unsigned long long below = (lane == 63) ? 0x7FFFFFFFFFFFFFFFull
                                                  : ((1ull << lane) - 1ull);

    int base8[NPART];
    #pragma unroll
    for (int pp = 0; pp < NPART; ++pp) base8[pp] = wbase[pp * nw + gw];

    const int tiles = (n_edges + 255) >> 8;
    for (int t = gw; t < tiles; t += nw) {
        const int base = (t << 8) + (lane << 2);
        int p[4]; unsigned pk[4];
        if (base + 3 < n_edges) {
            const int4 d4 = *(const int4*)(dst + base);
            const int4 s4 = *(const int4*)(src + base);
            p[0] = d4.x / part_sz; pk[0] = ((unsigned)(d4.x - p[0] * part_sz) << 17) | (unsigned)s4.x;
            p[1] = d4.y / part_sz; pk[1] = ((unsigned)(d4.y - p[1] * part_sz) << 17) | (unsigned)s4.y;
            p[2] = d4.z / part_sz; pk[2] = ((unsigned)(d4.z - p[2] * part_sz) << 17) | (unsigned)s4.z;
            p[3] = d4.w / part_sz; pk[3] = ((unsigned)(d4.w - p[3] * part_sz) << 17) | (unsigned)s4.w;
        } else {
            #pragma unroll
            for (int j = 0; j < 4; ++j) {
                if (base + j < n_edges) {
                    const int d = dst[base + j];
                    p[j] = d / part_sz;
                    pk[j] = ((unsigned)(d - p[j] * part_sz) << 17) | (unsigned)src[base + j];
                } else p[j] = -1;
            }
        }
        #pragma unroll
        for (int pp = 0; pp < NPART; ++pp) {
            const unsigned long long m0 = __ballot(p[0] == pp);
            const unsigned long long m1 = __ballot(p[1] == pp);
            const unsigned long long m2 = __ballot(p[2] == pp);
            const unsigned long long m3 = __ballot(p[3] == pp);
            const int k0 = __popcll(m0), k1 = __popcll(m1);
            const int k2 = __popcll(m2), k3 = __popcll(m3);
            const int go = base8[pp];
            if ((m0 >> lane) & 1) bkt[go + __popcll(m0 & below)] = pk[0];
            if ((m1 >> lane) & 1) bkt[go + k0 + __popcll(m1 & below)] = pk[1];
            if ((m2 >> lane) & 1) bkt[go + k0 + k1 + __popcll(m2 & below)] = pk[2];
            if ((m3 >> lane) & 1) bkt[go + k0 + k1 + k2 + __popcll(m3 & below)] = pk[3];
            base8[pp] = go + k0 + k1 + k2 + k3;
        }
    }
}

// ---------------------------------------------------------------------------
// LEVEL-2: sub-bucket split; sub = pk>>SUBSH (dst_local>>6): 64-node windows.
// ---------------------------------------------------------------------------
__global__ __launch_bounds__(256) void k_scount(
    const unsigned* __restrict__ bkt, const int* __restrict__ tot8,
    const int* __restrict__ off8, int* __restrict__ wcnt2, int nsub)
{
    __shared__ int lcnt[4][MAXNSUB];
    const int p = blockIdx.x & (NPART - 1);
    const int wv = threadIdx.x >> 6, lane = threadIdx.x & 63;
    const int w2 = (blockIdx.x >> 3) * 4 + wv;

    for (int i = lane; i < nsub; i += 64) lcnt[wv][i] = 0;

    const int nB = tot8[p];
    const unsigned* b = bkt + off8[p];
    const int nt = (nB + 255) >> 8;
    for (int t = w2; t < nt; t += 256) {
        const int base = (t << 8) + (lane << 2);
        if (base + 3 < nB) {
            const uint4 v = *(const uint4*)(b + base);
            atomicAdd(&lcnt[wv][v.x >> SUBSH], 1);
            atomicAdd(&lcnt[wv][v.y >> SUBSH], 1);
            atomicAdd(&lcnt[wv][v.z >> SUBSH], 1);
            atomicAdd(&lcnt[wv][v.w >> SUBSH], 1);
        } else {
            for (int j = 0; j < 4; ++j)
                if (base + j < nB) atomicAdd(&lcnt[wv][b[base + j] >> SUBSH], 1);
        }
    }
    for (int i = lane; i < nsub; i += 64)
        wcnt2[(p * nsub + i) * 256 + w2] = lcnt[wv][i];
}

__global__ __launch_bounds__(256) void k_sscan(
    int* __restrict__ wcnt2, int* __restrict__ tot2)
{
    __shared__ int buf[256];
    const int ps = blockIdx.x, tid = threadIdx.x;
    const int v = wcnt2[ps * 256 + tid];
    buf[tid] = v;
    __syncthreads();
    #pragma unroll
    for (int off = 1; off < 256; off <<= 1) {
        int t = (tid >= off) ? buf[tid - off] : 0;
        __syncthreads();
        buf[tid] += t;
        __syncthreads();
    }
    wcnt2[ps * 256 + tid] = buf[tid] - v;
    if (tid == 255) tot2[ps] = buf[255];
}

__global__ __launch_bounds__(256) void k_soff(
    const int* __restrict__ tot2, int* __restrict__ off2, int n)
{
    __shared__ int buf[256];
    const int tid = threadIdx.x;
    const int seg = (n + 255) >> 8;
    const int s0 = tid * seg, s1e = min(s0 + seg, n);
    int tsum = 0;
    for (int i = s0; i < s1e; ++i) tsum += tot2[i];
    buf[tid] = tsum;
    __syncthreads();
    #pragma unroll
    for (int off = 1; off < 256; off <<= 1) {
        int t = (tid >= off) ? buf[tid - off] : 0;
        __syncthreads();
        buf[tid] += t;
        __syncthreads();
    }
    int prefix = buf[tid] - tsum;
    for (int i = s0; i < s1e; ++i) {
        const int v = tot2[i];
        off2[i] = prefix;
        prefix += v;
    }
}

__global__ __launch_bounds__(256) void k_swrite(
    const unsigned* __restrict__ bkt, const int* __restrict__ tot8,
    const int* __restrict__ off8, const int* __restrict__ wcnt2,
    const int* __restrict__ off2, unsigned* __restrict__ bkt2, int nsub)
{
    __shared__ int lbase[4][MAXNSUB];
    const int p = blockIdx.x & (NPART - 1);
    const int wv = threadIdx.x >> 6, lane = threadIdx.x & 63;
    const int w2 = (blockIdx.x >> 3) * 4 + wv;

    for (int i = lane; i < nsub; i += 64)
        lbase[wv][i] = off2[p * nsub + i] + wcnt2[(p * nsub + i) * 256 + w2];

    const int nB = tot8[p];
    const unsigned* b = bkt + off8[p];
    const int nt = (nB + 255) >> 8;
    for (int t = w2; t < nt; t += 256) {
        const int base = (t << 8) + (lane << 2);
        if (base + 3 < nB) {
            const uint4 v = *(const uint4*)(b + base);
            bkt2[atomicAdd(&lbase[wv][v.x >> SUBSH], 1)] = v.x;
            bkt2[atomicAdd(&lbase[wv][v.y >> SUBSH], 1)] = v.y;
            bkt2[atomicAdd(&lbase[wv][v.z >> SUBSH], 1)] = v.z;
            bkt2[atomicAdd(&lbase[wv][v.w >> SUBSH], 1)] = v.w;
        } else {
            for (int j = 0; j < 4; ++j)
                if (base + j < nB) {
                    const unsigned pk = b[base + j];
                    bkt2[atomicAdd(&lbase[wv][pk >> SUBSH], 1)] = pk;
                }
        }
    }
}

// ---------------------------------------------------------------------------
// SORTED AGG (SUBW=64): counting sort in LDS with q precomputed;
// uniform-address reads; unroll-8; register racc/rden; 1568 blocks (6.1/CU).
// ---------------------------------------------------------------------------
__global__ __launch_bounds__(512) void k_sorted_agg(
    const unsigned* __restrict__ bkt2, const int* __restrict__ tot2,
    const int* __restrict__ off2,
    const float* __restrict__ s1, const float* __restrict__ s2,
    const ushort* __restrict__ zb, float* __restrict__ h,
    int n_nodes, int part_sz, int nsub)
{
    __shared__ uint2 sorted[CAP];      // 12 KB
    __shared__ int cnt[SUBW];
    __shared__ int scn[SUBW];
    __shared__ int cur[SUBW];

    const int p = blockIdx.x & (NPART - 1);
    const int sub = blockIdx.x >> 3;
    const int ps = p * nsub + sub;
    const int pbase = p * part_sz;
    const int wbase = sub * SUBW;
    const int psz = min(part_sz, n_nodes - pbase);
    const int wn = min(SUBW, psz - wbase);
    if (wn <= 0) return;

    const int tid = threadIdx.x, wv = tid >> 6, lane = tid & 63;

    if (tid < SUBW) cnt[tid] = 0;
    __syncthreads();

    int n2 = tot2[ps];
    if (n2 > CAP) n2 = CAP;   // defensive; mean 1020, sigma 32
    const unsigned* b = bkt2 + off2[ps];

    for (int i = tid; i < n2; i += 512)
        atomicAdd(&cnt[(b[i] >> 17) & (SUBW - 1)], 1);
    __syncthreads();

    if (tid < SUBW) scn[tid] = cnt[tid];
    __syncthreads();
    #pragma unroll
    for (int off = 1; off < SUBW; off <<= 1) {
        int t = 0;
        if (tid < SUBW && tid >= off) t = scn[tid - off];
        __syncthreads();
        if (tid < SUBW) scn[tid] += t;
        __syncthreads();
    }
    if (tid < SUBW) cur[tid] = scn[tid] - cnt[tid];
    __syncthreads();

    for (int i = tid; i < n2; i += 512) {
        const unsigned pk = b[i];
        const int sv = (int)(pk & 0x1FFFFu);
        const int dfull = (int)(pk >> 17);
        float e = s1[sv] + s2[pbase + dfull];
        e = e > 0.f ? e : 0.01f * e;
        const float q = __expf(e);
        const int pos = atomicAdd(&cur[dfull & (SUBW - 1)], 1);
        sorted[pos] = make_uint2(pk, __float_as_uint(q));
    }
    __syncthreads();

    // wave wv owns window-local nodes [nlo, nhi): 8 nodes per wave
    const int nlo = wv * 8;
    const int nhi = nlo + 8;
    const int lo = (nlo == 0) ? 0 : scn[nlo - 1];
    const int hi = scn[nhi - 1];

    float racc = 0.f, rden = 0.f;
    int curd = -1;
    int lastw = nlo - 1;

#define FLUSH() do { if (curd >= 0) { \
        for (int z_ = lastw + 1; z_ < curd; ++z_) \
            h[(size_t)(pbase + wbase + z_) * OUTD + lane] = 0.f; \
        h[(size_t)(pbase + wbase + curd) * OUTD + lane] = racc / fmaxf(rden, 1e-9f); \
        lastw = curd; } } while (0)

#define STEP2(D, Q, Z) do { \
        if ((D) != curd) { FLUSH(); curd = (D); racc = 0.f; rden = 0.f; } \
        racc = fmaf((Q), (Z), racc); rden += (Q); } while (0)

    int e = lo;
    for (; e + 7 < hi; e += 8) {
        const uint2 u0 = sorted[e + 0], u1 = sorted[e + 1];
        const uint2 u2 = sorted[e + 2], u3 = sorted[e + 3];
        const uint2 u4 = sorted[e + 4], u5 = sorted[e + 5];
        const uint2 u6 = sorted[e + 6], u7 = sorted[e + 7];
        const float z0 = bf2f(zb[(size_t)(u0.x & 0x1FFFFu) * OUTD + lane]);
        const float z1 = bf2f(zb[(size_t)(u1.x & 0x1FFFFu) * OUTD + lane]);
        const float z2 = bf2f(zb[(size_t)(u2.x & 0x1FFFFu) * OUTD + lane]);
        const float z3 = bf2f(zb[(size_t)(u3.x & 0x1FFFFu) * OUTD + lane]);
        const float z4 = bf2f(zb[(size_t)(u4.x & 0x1FFFFu) * OUTD + lane]);
        const float z5 = bf2f(zb[(size_t)(u5.x & 0x1FFFFu) * OUTD + lane]);
        const float z6 = bf2f(zb[(size_t)(u6.x & 0x1FFFFu) * OUTD + lane]);
        const float z7 = bf2f(zb[(size_t)(u7.x & 0x1FFFFu) * OUTD + lane]);
        STEP2((int)((u0.x >> 17) & (SUBW - 1)), __uint_as_float(u0.y), z0);
        STEP2((int)((u1.x >> 17) & (SUBW - 1)), __uint_as_float(u1.y), z1);
        STEP2((int)((u2.x >> 17) & (SUBW - 1)), __uint_as_float(u2.y), z2);
        STEP2((int)((u3.x >> 17) & (SUBW - 1)), __uint_as_float(u3.y), z3);
        STEP2((int)((u4.x >> 17) & (SUBW - 1)), __uint_as_float(u4.y), z4);
        STEP2((int)((u5.x >> 17) & (SUBW - 1)), __uint_as_float(u5.y), z5);
        STEP2((int)((u6.x >> 17) & (SUBW - 1)), __uint_as_float(u6.y), z6);
        STEP2((int)((u7.x >> 17) & (SUBW - 1)), __uint_as_float(u7.y), z7);
    }
    for (; e < hi; ++e) {
        const uint2 u = sorted[e];
        const float z = bf2f(zb[(size_t)(u.x & 0x1FFFFu) * OUTD + lane]);
        STEP2((int)((u.x >> 17) & (SUBW - 1)), __uint_as_float(u.y), z);
    }
    FLUSH();
    const int zend = min(nhi, wn);
    for (int z = lastw + 1; z < zend; ++z)
        h[(size_t)(pbase + wbase + z) * OUTD + lane] = 0.f;
#undef STEP2
#undef FLUSH
}

extern "C" void kernel_launch(void* const* d_in, const int* in_sizes, int n_in,
                              void* d_out, int out_size, void* d_ws, size_t ws_size,
                              hipStream_t stream)
{
    const float* x    = (const float*)d_in[0];
    const float* w_in = (const float*)d_in[1];
    const float* b_in = (const float*)d_in[2];
    const float* w    = (const float*)d_in[3];
    const float* a    = (const float*)d_in[4];
    const int*   src  = (const int*)d_in[5];
    const int*   dst  = (const int*)d_in[6];
    const int n_nodes = in_sizes[0] / IN_DIM;
    const int n_edges = in_sizes[5];

    float* h = (float*)d_out;

    const int NW = BKT_BLOCKS * 4;
    const int part_sz = (n_nodes + NPART - 1) / NPART;
    const int nsub = (part_sz + SUBW - 1) / SUBW;  // 196 <= MAXNSUB

    // workspace (~24 MB)
    ushort*   zb    = (ushort*)d_ws;                      // n_nodes*64 bf16
    float*    s1    = (float*)(zb + (size_t)n_nodes * OUTD);
    float*    s2    = s1 + n_nodes;
    int*      tot8  = (int*)(s2 + n_nodes);               // 8
    int*      off8  = tot8 + NPART;                       // 9 (region padded to 64)
    int*      wcnt  = tot8 + 64;                          // 8*NW
    int*      wcnt2 = wcnt + NPART * NW;                  // 8*MAXNSUB*256
    int*      tot2  = wcnt2 + NPART * MAXNSUB * 256;      // 8*MAXNSUB
    int*      off2  = tot2 + NPART * MAXNSUB;             // 8*MAXNSUB
    unsigned* bkt   = (unsigned*)(off2 + NPART * MAXNSUB);// n_edges
    unsigned* bkt2  = bkt + n_edges;                      // n_edges

    const int ntiles = (n_nodes + 63) / 64;
    const int nps = NPART * nsub;

    k_proj_bcount<<<PROJ_BLOCKS + BKT_BLOCKS, 256, 0, stream>>>(
        x, w_in, b_in, w, a, zb, s1, s2, dst, wcnt,
        n_nodes, ntiles, n_edges, part_sz);

    k_wscan<<<NPART, 256, 0, stream>>>(wcnt, tot8, off8, NW);
    k_bwrite<<<BKT_BLOCKS, 256, 0, stream>>>(src, dst, wcnt, bkt, n_edges, part_sz);

    k_scount<<<L2_BLOCKS, 256, 0, stream>>>(bkt, tot8, off8, wcnt2, nsub);
    k_sscan<<<nps, 256, 0, stream>>>(wcnt2, tot2);
    k_soff<<<1, 256, 0, stream>>>(tot2, off2, nps);
    k_swrite<<<L2_BLOCKS, 256, 0, stream>>>(bkt, tot8, off8, wcnt2, off2, bkt2, nsub);

    k_sorted_agg<<<nps, 512, 0, stream>>>(bkt2, tot2, off2, s1, s2, zb,
                                          h, n_nodes, part_sz, nsub);
}

// Round 16
// 126.493 us; speedup vs baseline: 1.0119x; 1.0119x over previous
//
#include <hip/hip_runtime.h>
#include <hip/hip_bf16.h>

#define IN_DIM 128
#define HID    64
#define OUTD   64
#define NPART  8
#define SUBW   128           // nodes per level-2 window (power of 2)
#define CAP    3072          // fixed sorted-edge slot per (p,sub); mean 2041 sigma 45
#define PROJ_BLOCKS 1043
#define BKT_BLOCKS 1024      // level-1 radix: NW = 4096 waves
#define L2_BLOCKS 512

typedef __attribute__((ext_vector_type(8))) short bf16x8;
typedef __attribute__((ext_vector_type(4))) float f32x4;

__device__ __forceinline__ float gelu_exact(float v) {
    return v * 0.5f * (1.0f + erff(v * 0.70710678118654752f));
}
__device__ __forceinline__ short f2bf(float f) {
    __hip_bfloat16 b = __float2bfloat16(f);   // RNE
    return *reinterpret_cast<short*>(&b);
}
__device__ __forceinline__ float bf2f(ushort u) {
    return __uint_as_float(((unsigned)u) << 16);
}

// ---------------------------------------------------------------------------
// FUSED K1: blocks [0,PROJ_BLOCKS) = MFMA node projection; rest = level-1
// count (ballot, no atomics). Independent -> concurrent.
// ---------------------------------------------------------------------------
__global__ __launch_bounds__(256) void k_proj_bcount(
    const float* __restrict__ x, const float* __restrict__ w_in,
    const float* __restrict__ b_in, const float* __restrict__ w,
    const float* __restrict__ a,
    ushort* __restrict__ zb, float* __restrict__ s1, float* __restrict__ s2,
    const int* __restrict__ dst, int* __restrict__ wcnt,
    int n_nodes, int ntiles, int n_edges, int part_sz)
{
    __shared__ ushort h0s[4][16 * 64];

    const int tid = threadIdx.x;

    if (blockIdx.x < PROJ_BLOCKS) {
        const int wv = tid >> 6, l = tid & 63;
        const int c = l & 15, g = l >> 4;

        bf16x8 B1[4][4];
        #pragma unroll
        for (int s = 0; s < 4; ++s)
            #pragma unroll
            for (int t = 0; t < 4; ++t) {
                bf16x8 f;
                #pragma unroll
                for (int e = 0; e < 8; ++e)
                    f[e] = f2bf(w_in[(s * 32 + g * 8 + e) * HID + t * 16 + c]);
                B1[s][t] = f;
            }
        bf16x8 B2[2][4];
        #pragma unroll
        for (int s = 0; s < 2; ++s)
            #pragma unroll
            for (int t = 0; t < 4; ++t) {
                bf16x8 f;
                #pragma unroll
                for (int e = 0; e < 8; ++e)
                    f[e] = f2bf(w[(s * 32 + g * 8 + e) * OUTD + t * 16 + c]);
                B2[s][t] = f;
            }
        float bias[4], a1c[4], a2c[4];
        #pragma unroll
        for (int t = 0; t < 4; ++t) {
            bias[t] = b_in[t * 16 + c];
            a1c[t]  = a[t * 16 + c];
            a2c[t]  = a[OUTD + t * 16 + c];
        }

        ushort* hrow = &h0s[wv][0];

        for (int tile = blockIdx.x; tile < ntiles; tile += PROJ_BLOCKS) {
            const int nbase = tile * 64 + wv * 16;

            const int row = min(nbase + c, n_nodes - 1);
            const float* xp = x + (size_t)row * IN_DIM;
            bf16x8 A1[4];
            #pragma unroll
            for (int s = 0; s < 4; ++s) {
                const float4 u0 = *(const float4*)(xp + s * 32 + g * 8);
                const float4 u1 = *(const float4*)(xp + s * 32 + g * 8 + 4);
                bf16x8 f;
                f[0] = f2bf(u0.x); f[1] = f2bf(u0.y); f[2] = f2bf(u0.z); f[3] = f2bf(u0.w);
                f[4] = f2bf(u1.x); f[5] = f2bf(u1.y); f[6] = f2bf(u1.z); f[7] = f2bf(u1.w);
                A1[s] = f;
            }

            #pragma unroll
            for (int t = 0; t < 4; ++t) {
                f32x4 acc = {0.f, 0.f, 0.f, 0.f};
                #pragma unroll
                for (int s = 0; s < 4; ++s)
                    acc = __builtin_amdgcn_mfma_f32_16x16x32_bf16(A1[s], B1[s][t], acc, 0, 0, 0);
                #pragma unroll
                for (int r = 0; r < 4; ++r) {
                    const int m = g * 4 + r;
                    const int n = t * 16 + c;
                    const float h0 = gelu_exact(acc[r] + bias[t]);
                    hrow[m * 64 + (n ^ ((m & 7) << 3))] = (ushort)f2bf(h0);
                }
            }
            __syncthreads();

            bf16x8 A2[2];
            #pragma unroll
            for (int s = 0; s < 2; ++s) {
                const int k = s * 32 + g * 8;
                A2[s] = *(const bf16x8*)(hrow + c * 64 + (k ^ ((c & 7) << 3)));
            }

            f32x4 C2[4];
            #pragma unroll
            for (int t = 0; t < 4; ++t) {
                f32x4 acc = {0.f, 0.f, 0.f, 0.f};
                acc = __builtin_amdgcn_mfma_f32_16x16x32_bf16(A2[0], B2[0][t], acc, 0, 0, 0);
                acc = __builtin_amdgcn_mfma_f32_16x16x32_bf16(A2[1], B2[1][t], acc, 0, 0, 0);
                C2[t] = acc;
            }

            float p1v[4] = {0.f, 0.f, 0.f, 0.f}, p2v[4] = {0.f, 0.f, 0.f, 0.f};
            #pragma unroll
            for (int t = 0; t < 4; ++t)
                #pragma unroll
                for (int r = 0; r < 4; ++r) {
                    p1v[r] = fmaf(C2[t][r], a1c[t], p1v[r]);
                    p2v[r] = fmaf(C2[t][r], a2c[t], p2v[r]);
                    const int node = nbase + g * 4 + r;
                    if (node < n_nodes)
                        zb[(size_t)node * OUTD + t * 16 + c] = (ushort)f2bf(C2[t][r]);
                }

            #pragma unroll
            for (int r = 0; r < 4; ++r) {
                p1v[r] += __shfl_xor(p1v[r], 1, 64);
                p1v[r] += __shfl_xor(p1v[r], 2, 64);
                p1v[r] += __shfl_xor(p1v[r], 4, 64);
                p1v[r] += __shfl_xor(p1v[r], 8, 64);
                p2v[r] += __shfl_xor(p2v[r], 1, 64);
                p2v[r] += __shfl_xor(p2v[r], 2, 64);
                p2v[r] += __shfl_xor(p2v[r], 4, 64);
                p2v[r] += __shfl_xor(p2v[r], 8, 64);
            }
            const float v1 = (c == 0) ? p1v[0] : (c == 1) ? p1v[1] : (c == 2) ? p1v[2] : p1v[3];
            const float v2 = (c == 0) ? p2v[0] : (c == 1) ? p2v[1] : (c == 2) ? p2v[2] : p2v[3];
            const int snode = nbase + g * 4 + c;
            if (c < 4 && snode < n_nodes) { s1[snode] = v1; s2[snode] = v2; }
            __syncthreads();
        }
    } else {
        const int bid = blockIdx.x - PROJ_BLOCKS;
        const int lane = tid & 63;
        const int gw = (bid * 256 + tid) >> 6;
        const int nw = (BKT_BLOCKS * 256) >> 6;

        int cnt[NPART];
        #pragma unroll
        for (int p = 0; p < NPART; ++p) cnt[p] = 0;

        const int tiles = (n_edges + 255) >> 8;
        for (int t = gw; t < tiles; t += nw) {
            const int base = (t << 8) + (lane << 2);
            int p0 = -1, p1 = -1, p2 = -1, p3 = -1;
            if (base + 3 < n_edges) {
                const int4 d4 = *(const int4*)(dst + base);
                p0 = d4.x / part_sz; p1 = d4.y / part_sz;
                p2 = d4.z / part_sz; p3 = d4.w / part_sz;
            } else {
                if (base + 0 < n_edges) p0 = dst[base + 0] / part_sz;
                if (base + 1 < n_edges) p1 = dst[base + 1] / part_sz;
                if (base + 2 < n_edges) p2 = dst[base + 2] / part_sz;
                if (base + 3 < n_edges) p3 = dst[base + 3] / part_sz;
            }
            #pragma unroll
            for (int pp = 0; pp < NPART; ++pp) {
                cnt[pp] += __popcll(__ballot(p0 == pp)) + __popcll(__ballot(p1 == pp))
                         + __popcll(__ballot(p2 == pp)) + __popcll(__ballot(p3 == pp));
            }
        }
        if (lane == 0) {
            #pragma unroll
            for (int pp = 0; pp < NPART; ++pp) wcnt[pp * nw + gw] = cnt[pp];
        }
    }
}

// ---------------------------------------------------------------------------
// Level-1 scan (merged totals + off8 + per-wave bases; segmented, 1 block scan)
// ---------------------------------------------------------------------------
__global__ __launch_bounds__(256) void k_wscan(
    int* __restrict__ wcnt, int* __restrict__ tot8,
    int* __restrict__ off8, int nw)
{
    __shared__ int buf[256];
    __shared__ int sums[NPART];
    const int p = blockIdx.x, tid = threadIdx.x;
    const int seg = (nw + 255) >> 8;
    const int s0 = tid * seg, s1e = min(s0 + seg, nw);

    for (int q = 0; q < NPART; ++q) {
        int s = 0;
        for (int i = s0; i < s1e; ++i) s += wcnt[q * nw + i];
        buf[tid] = s;
        __syncthreads();
        #pragma unroll
        for (int off = 128; off; off >>= 1) {
            if (tid < off) buf[tid] += buf[tid + off];
            __syncthreads();
        }
        if (tid == 0) sums[q] = buf[0];
        __syncthreads();
    }
    if (tid == 0) {
        tot8[p] = sums[p];
        if (p == 0) {
            int a = 0;
            for (int q = 0; q < NPART; ++q) { off8[q] = a; a += sums[q]; }
        }
    }
    int running = 0;
    for (int q = 0; q < p; ++q) running += sums[q];

    int tsum = 0;
    for (int i = s0; i < s1e; ++i) tsum += wcnt[p * nw + i];
    buf[tid] = tsum;
    __syncthreads();
    #pragma unroll
    for (int off = 1; off < 256; off <<= 1) {
        int t = (tid >= off) ? buf[tid - off] : 0;
        __syncthreads();
        buf[tid] += t;
        __syncthreads();
    }
    int prefix = running + buf[tid] - tsum;
    for (int i = s0; i < s1e; ++i) {
        const int v = wcnt[p * nw + i];
        wcnt[p * nw + i] = prefix;
        prefix += v;
    }
}

__global__ __launch_bounds__(256) void k_bwrite(
    const int* __restrict__ src, const int* __restrict__ dst,
    const int* __restrict__ wbase, unsigned* __restrict__ bkt,
    int n_edges, int part_sz)
{
    const int lane = threadIdx.x & 63;
    const int gw = (blockIdx.x * 256 + threadIdx.x) >> 6;
    const int nw = (gridDim.x * 256) >> 6;
    const unsigned long long below = (lane == 63) ? 0x7FFFFFFFFFFFFFFFull
                                                  : ((1ull << lane) - 1ull);

    int base8[NPART];
    #pragma unroll
    for (int pp = 0; pp < NPART; ++pp) base8[pp] = wbase[pp * nw + gw];

    const int tiles = (n_edges + 255) >> 8;
    for (int t = gw; t < tiles; t += nw) {
        const int base = (t << 8) + (lane << 2);
        int p[4]; unsigned pk[4];
        if (base + 3 < n_edges) {
            const int4 d4 = *(const int4*)(dst + base);
            const int4 s4 = *(const int4*)(src + base);
            p[0] = d4.x / part_sz; pk[0] = ((unsigned)(d4.x - p[0] * part_sz) << 17) | (unsigned)s4.x;
            p[1] = d4.y / part_sz; pk[1] = ((unsigned)(d4.y - p[1] * part_sz) << 17) | (unsigned)s4.y;
            p[2] = d4.z / part_sz; pk[2] = ((unsigned)(d4.z - p[2] * part_sz) << 17) | (unsigned)s4.z;
            p[3] = d4.w / part_sz; pk[3] = ((unsigned)(d4.w - p[3] * part_sz) << 17) | (unsigned)s4.w;
        } else {
            #pragma unroll
            for (int j = 0; j < 4; ++j) {
                if (base + j < n_edges) {
                    const int d = dst[base + j];
                    p[j] = d / part_sz;
                    pk[j] = ((unsigned)(d - p[j] * part_sz) << 17) | (unsigned)src[base + j];
                } else p[j] = -1;
            }
        }
        #pragma unroll
        for (int pp = 0; pp < NPART; ++pp) {
            const unsigned long long m0 = __ballot(p[0] == pp);
            const unsigned long long m1 = __ballot(p[1] == pp);
            const unsigned long long m2 = __ballot(p[2] == pp);
            const unsigned long long m3 = __ballot(p[3] == pp);
            const int k0 = __popcll(m0), k1 = __popcll(m1);
            const int k2 = __popcll(m2), k3 = __popcll(m3);
            const int go = base8[pp];
            if ((m0 >> lane) & 1) bkt[go + __popcll(m0 & below)] = pk[0];
            if ((m1 >> lane) & 1) bkt[go + k0 + __popcll(m1 & below)] = pk[1];
            if ((m2 >> lane) & 1) bkt[go + k0 + k1 + __popcll(m2 & below)] = pk[2];
            if ((m3 >> lane) & 1) bkt[go + k0 + k1 + k2 + __popcll(m3 & below)] = pk[3];
            base8[pp] = go + k0 + k1 + k2 + k3;
        }
    }
}

// ---------------------------------------------------------------------------
// LEVEL-2: sub-bucket split; sub = pk>>24 (dst_local>>7): 128-node windows.
// bkt2 uses STATIC per-(p,sub) slots of CAP entries -> no global offset scan.
// ---------------------------------------------------------------------------
__global__ __launch_bounds__(256) void k_scount(
    const unsigned* __restrict__ bkt, const int* __restrict__ tot8,
    const int* __restrict__ off8, int* __restrict__ wcnt2, int nsub)
{
    __shared__ int lcnt[4][SUBW];
    const int p = blockIdx.x & (NPART - 1);
    const int wv = threadIdx.x >> 6, lane = threadIdx.x & 63;
    const int w2 = (blockIdx.x >> 3) * 4 + wv;

    for (int i = lane; i < nsub; i += 64) lcnt[wv][i] = 0;

    const int nB = tot8[p];
    const unsigned* b = bkt + off8[p];
    const int nt = (nB + 255) >> 8;
    for (int t = w2; t < nt; t += 256) {
        const int base = (t << 8) + (lane << 2);
        if (base + 3 < nB) {
            const uint4 v = *(const uint4*)(b + base);
            atomicAdd(&lcnt[wv][v.x >> 24], 1);
            atomicAdd(&lcnt[wv][v.y >> 24], 1);
            atomicAdd(&lcnt[wv][v.z >> 24], 1);
            atomicAdd(&lcnt[wv][v.w >> 24], 1);
        } else {
            for (int j = 0; j < 4; ++j)
                if (base + j < nB) atomicAdd(&lcnt[wv][b[base + j] >> 24], 1);
        }
    }
    for (int i = lane; i < nsub; i += 64)
        wcnt2[(p * nsub + i) * 256 + w2] = lcnt[wv][i];
}

__global__ __launch_bounds__(256) void k_sscan(
    int* __restrict__ wcnt2, int* __restrict__ tot2)
{
    __shared__ int buf[256];
    const int ps = blockIdx.x, tid = threadIdx.x;
    const int v = wcnt2[ps * 256 + tid];
    buf[tid] = v;
    __syncthreads();
    #pragma unroll
    for (int off = 1; off < 256; off <<= 1) {
        int t = (tid >= off) ? buf[tid - off] : 0;
        __syncthreads();
        buf[tid] += t;
        __syncthreads();
    }
    wcnt2[ps * 256 + tid] = buf[tid] - v;   // exclusive within sub-bucket
    if (tid == 255) tot2[ps] = buf[255];
}

__global__ __launch_bounds__(256) void k_swrite(
    const unsigned* __restrict__ bkt, const int* __restrict__ tot8,
    const int* __restrict__ off8, const int* __restrict__ wcnt2,
    unsigned* __restrict__ bkt2, int nsub)
{
    __shared__ int lbase[4][SUBW];
    const int p = blockIdx.x & (NPART - 1);
    const int wv = threadIdx.x >> 6, lane = threadIdx.x & 63;
    const int w2 = (blockIdx.x >> 3) * 4 + wv;

    for (int i = lane; i < nsub; i += 64)
        lbase[wv][i] = (p * nsub + i) * CAP + wcnt2[(p * nsub + i) * 256 + w2];

    const int nB = tot8[p];
    const unsigned* b = bkt + off8[p];
    const int nt = (nB + 255) >> 8;
    for (int t = w2; t < nt; t += 256) {
        const int base = (t << 8) + (lane << 2);
        if (base + 3 < nB) {
            const uint4 v = *(const uint4*)(b + base);
            bkt2[atomicAdd(&lbase[wv][v.x >> 24], 1)] = v.x;
            bkt2[atomicAdd(&lbase[wv][v.y >> 24], 1)] = v.y;
            bkt2[atomicAdd(&lbase[wv][v.z >> 24], 1)] = v.z;
            bkt2[atomicAdd(&lbase[wv][v.w >> 24], 1)] = v.w;
        } else {
            for (int j = 0; j < 4; ++j)
                if (base + j < nB) {
                    const unsigned pk = b[base + j];
                    bkt2[atomicAdd(&lbase[wv][pk >> 24], 1)] = pk;
                }
        }
    }
}

// ---------------------------------------------------------------------------
// SORTED AGG (R14-proven: SUBW=128, 512 threads): counting sort in LDS with
// q precomputed; uniform-address reads; unroll-8; register racc/rden.
// ---------------------------------------------------------------------------
__global__ __launch_bounds__(512) void k_sorted_agg(
    const unsigned* __restrict__ bkt2, const int* __restrict__ tot2,
    const float* __restrict__ s1, const float* __restrict__ s2,
    const ushort* __restrict__ zb, float* __restrict__ h,
    int n_nodes, int part_sz, int nsub)
{
    __shared__ uint2 sorted[CAP];      // 24 KB
    __shared__ int cnt[SUBW];
    __shared__ int scn[SUBW];
    __shared__ int cur[SUBW];

    const int p = blockIdx.x & (NPART - 1);
    const int sub = blockIdx.x >> 3;
    const int ps = p * nsub + sub;
    const int pbase = p * part_sz;
    const int wbase = sub * SUBW;
    const int psz = min(part_sz, n_nodes - pbase);
    const int wn = min(SUBW, psz - wbase);
    if (wn <= 0) return;

    const int tid = threadIdx.x, wv = tid >> 6, lane = tid & 63;

    if (tid < SUBW) cnt[tid] = 0;
    __syncthreads();

    int n2 = tot2[ps];
    if (n2 > CAP) n2 = CAP;   // defensive; mean 2041, sigma 45
    const unsigned* b = bkt2 + (size_t)ps * CAP;

    for (int i = tid; i < n2; i += 512)
        atomicAdd(&cnt[(b[i] >> 17) & (SUBW - 1)], 1);
    __syncthreads();

    if (tid < SUBW) scn[tid] = cnt[tid];
    __syncthreads();
    #pragma unroll
    for (int off = 1; off < SUBW; off <<= 1) {
        int t = 0;
        if (tid < SUBW && tid >= off) t = scn[tid - off];
        __syncthreads();
        if (tid < SUBW) scn[tid] += t;
        __syncthreads();
    }
    if (tid < SUBW) cur[tid] = scn[tid] - cnt[tid];
    __syncthreads();

    for (int i = tid; i < n2; i += 512) {
        const unsigned pk = b[i];
        const int sv = (int)(pk & 0x1FFFFu);
        const int dfull = (int)(pk >> 17);
        float e = s1[sv] + s2[pbase + dfull];
        e = e > 0.f ? e : 0.01f * e;
        const float q = __expf(e);
        const int pos = atomicAdd(&cur[dfull & (SUBW - 1)], 1);
        sorted[pos] = make_uint2(pk, __float_as_uint(q));
    }
    __syncthreads();

    // wave wv owns window-local nodes [nlo, nhi): 16 nodes per wave
    const int nlo = wv * 16;
    const int nhi = nlo + 16;
    const int lo = (nlo == 0) ? 0 : scn[nlo - 1];
    const int hi = scn[nhi - 1];

    float racc = 0.f, rden = 0.f;
    int curd = -1;
    int lastw = nlo - 1;

#define FLUSH() do { if (curd >= 0) { \
        for (int z_ = lastw + 1; z_ < curd; ++z_) \
            h[(size_t)(pbase + wbase + z_) * OUTD + lane] = 0.f; \
        h[(size_t)(pbase + wbase + curd) * OUTD + lane] = racc / fmaxf(rden, 1e-9f); \
        lastw = curd; } } while (0)

#define STEP2(D, Q, Z) do { \
        if ((D) != curd) { FLUSH(); curd = (D); racc = 0.f; rden = 0.f; } \
        racc = fmaf((Q), (Z), racc); rden += (Q); } while (0)

    int e = lo;
    for (; e + 7 < hi; e += 8) {
        const uint2 u0 = sorted[e + 0], u1 = sorted[e + 1];
        const uint2 u2 = sorted[e + 2], u3 = sorted[e + 3];
        const uint2 u4 = sorted[e + 4], u5 = sorted[e + 5];
        const uint2 u6 = sorted[e + 6], u7 = sorted[e + 7];
        const float z0 = bf2f(zb[(size_t)(u0.x & 0x1FFFFu) * OUTD + lane]);
        const float z1 = bf2f(zb[(size_t)(u1.x & 0x1FFFFu) * OUTD + lane]);
        const float z2 = bf2f(zb[(size_t)(u2.x & 0x1FFFFu) * OUTD + lane]);
        const float z3 = bf2f(zb[(size_t)(u3.x & 0x1FFFFu) * OUTD + lane]);
        const float z4 = bf2f(zb[(size_t)(u4.x & 0x1FFFFu) * OUTD + lane]);
        const float z5 = bf2f(zb[(size_t)(u5.x & 0x1FFFFu) * OUTD + lane]);
        const float z6 = bf2f(zb[(size_t)(u6.x & 0x1FFFFu) * OUTD + lane]);
        const float z7 = bf2f(zb[(size_t)(u7.x & 0x1FFFFu) * OUTD + lane]);
        STEP2((int)((u0.x >> 17) & (SUBW - 1)), __uint_as_float(u0.y), z0);
        STEP2((int)((u1.x >> 17) & (SUBW - 1)), __uint_as_float(u1.y), z1);
        STEP2((int)((u2.x >> 17) & (SUBW - 1)), __uint_as_float(u2.y), z2);
        STEP2((int)((u3.x >> 17) & (SUBW - 1)), __uint_as_float(u3.y), z3);
        STEP2((int)((u4.x >> 17) & (SUBW - 1)), __uint_as_float(u4.y), z4);
        STEP2((int)((u5.x >> 17) & (SUBW - 1)), __uint_as_float(u5.y), z5);
        STEP2((int)((u6.x >> 17) & (SUBW - 1)), __uint_as_float(u6.y), z6);
        STEP2((int)((u7.x >> 17) & (SUBW - 1)), __uint_as_float(u7.y), z7);
    }
    for (; e < hi; ++e) {
        const uint2 u = sorted[e];
        const float z = bf2f(zb[(size_t)(u.x & 0x1FFFFu) * OUTD + lane]);
        STEP2((int)((u.x >> 17) & (SUBW - 1)), __uint_as_float(u.y), z);
    }
    FLUSH();
    const int zend = min(nhi, wn);
    for (int z = lastw + 1; z < zend; ++z)
        h[(size_t)(pbase + wbase + z) * OUTD + lane] = 0.f;
#undef STEP2
#undef FLUSH
}

extern "C" void kernel_launch(void* const* d_in, const int* in_sizes, int n_in,
                              void* d_out, int out_size, void* d_ws, size_t ws_size,
                              hipStream_t stream)
{
    const float* x    = (const float*)d_in[0];
    const float* w_in = (const float*)d_in[1];
    const float* b_in = (const float*)d_in[2];
    const float* w    = (const float*)d_in[3];
    const float* a    = (const float*)d_in[4];
    const int*   src  = (const int*)d_in[5];
    const int*   dst  = (const int*)d_in[6];
    const int n_nodes = in_sizes[0] / IN_DIM;
    const int n_edges = in_sizes[5];

    float* h = (float*)d_out;

    const int NW = BKT_BLOCKS * 4;
    const int part_sz = (n_nodes + NPART - 1) / NPART;
    const int nsub = (part_sz + SUBW - 1) / SUBW;  // 98 for n=100000
    const int nps = NPART * nsub;

    // workspace (~31 MB): zb | s1 | s2 | tot8/off8 | wcnt | wcnt2 | tot2 | bkt | bkt2
    ushort*   zb    = (ushort*)d_ws;                      // n_nodes*64 bf16
    float*    s1    = (float*)(zb + (size_t)n_nodes * OUTD);
    float*    s2    = s1 + n_nodes;
    int*      tot8  = (int*)(s2 + n_nodes);               // 8
    int*      off8  = tot8 + NPART;                       // 9 (region padded to 64)
    int*      wcnt  = tot8 + 64;                          // 8*NW
    int*      wcnt2 = wcnt + NPART * NW;                  // 8*128*256
    int*      tot2  = wcnt2 + NPART * 128 * 256;          // 8*128
    unsigned* bkt   = (unsigned*)(tot2 + NPART * 128);    // n_edges
    unsigned* bkt2  = bkt + n_edges;                      // nps*CAP (9.6 MB)

    const int ntiles = (n_nodes + 63) / 64;

    k_proj_bcount<<<PROJ_BLOCKS + BKT_BLOCKS, 256, 0, stream>>>(
        x, w_in, b_in, w, a, zb, s1, s2, dst, wcnt,
        n_nodes, ntiles, n_edges, part_sz);

    k_wscan<<<NPART, 256, 0, stream>>>(wcnt, tot8, off8, NW);
    k_bwrite<<<BKT_BLOCKS, 256, 0, stream>>>(src, dst, wcnt, bkt, n_edges, part_sz);

    k_scount<<<L2_BLOCKS, 256, 0, stream>>>(bkt, tot8, off8, wcnt2, nsub);
    k_sscan<<<nps, 256, 0, stream>>>(wcnt2, tot2);
    k_swrite<<<L2_BLOCKS, 256, 0, stream>>>(bkt, tot8, off8, wcnt2, bkt2, nsub);

    k_sorted_agg<<<nps, 512, 0, stream>>>(bkt2, tot2, s1, s2, zb,
                                          h, n_nodes, part_sz, nsub);
}

// Round 17
// 117.226 us; speedup vs baseline: 1.0919x; 1.0790x over previous
//
#include <hip/hip_runtime.h>
#include <hip/hip_bf16.h>

#define IN_DIM 128
#define HID    64
#define OUTD   64
#define NPART  8
#define SUBW   128           // nodes per level-2 window (power of 2)
#define CAP    3072          // fixed sorted-edge slot per (p,sub); mean 2041 sigma 45
#define PROJ_BLOCKS 1043
#define BKT_BLOCKS 1024      // level-1 radix: NW = 4096 waves
#define L2_BLOCKS 512

typedef __attribute__((ext_vector_type(8))) short bf16x8;
typedef __attribute__((ext_vector_type(4))) float f32x4;

__device__ __forceinline__ float gelu_exact(float v) {
    return v * 0.5f * (1.0f + erff(v * 0.70710678118654752f));
}
__device__ __forceinline__ short f2bf(float f) {
    __hip_bfloat16 b = __float2bfloat16(f);   // RNE
    return *reinterpret_cast<short*>(&b);
}
__device__ __forceinline__ float bf2f(ushort u) {
    return __uint_as_float(((unsigned)u) << 16);
}

// ---------------------------------------------------------------------------
// FUSED K1: blocks [0,PROJ_BLOCKS) = MFMA node projection; rest = level-1
// count (ballot, no atomics). Independent -> concurrent.
// ---------------------------------------------------------------------------
__global__ __launch_bounds__(256) void k_proj_bcount(
    const float* __restrict__ x, const float* __restrict__ w_in,
    const float* __restrict__ b_in, const float* __restrict__ w,
    const float* __restrict__ a,
    ushort* __restrict__ zb, float* __restrict__ s1, float* __restrict__ s2,
    const int* __restrict__ dst, int* __restrict__ wcnt,
    int n_nodes, int ntiles, int n_edges, int part_sz)
{
    __shared__ ushort h0s[4][16 * 64];

    const int tid = threadIdx.x;

    if (blockIdx.x < PROJ_BLOCKS) {
        const int wv = tid >> 6, l = tid & 63;
        const int c = l & 15, g = l >> 4;

        bf16x8 B1[4][4];
        #pragma unroll
        for (int s = 0; s < 4; ++s)
            #pragma unroll
            for (int t = 0; t < 4; ++t) {
                bf16x8 f;
                #pragma unroll
                for (int e = 0; e < 8; ++e)
                    f[e] = f2bf(w_in[(s * 32 + g * 8 + e) * HID + t * 16 + c]);
                B1[s][t] = f;
            }
        bf16x8 B2[2][4];
        #pragma unroll
        for (int s = 0; s < 2; ++s)
            #pragma unroll
            for (int t = 0; t < 4; ++t) {
                bf16x8 f;
                #pragma unroll
                for (int e = 0; e < 8; ++e)
                    f[e] = f2bf(w[(s * 32 + g * 8 + e) * OUTD + t * 16 + c]);
                B2[s][t] = f;
            }
        float bias[4], a1c[4], a2c[4];
        #pragma unroll
        for (int t = 0; t < 4; ++t) {
            bias[t] = b_in[t * 16 + c];
            a1c[t]  = a[t * 16 + c];
            a2c[t]  = a[OUTD + t * 16 + c];
        }

        ushort* hrow = &h0s[wv][0];

        for (int tile = blockIdx.x; tile < ntiles; tile += PROJ_BLOCKS) {
            const int nbase = tile * 64 + wv * 16;

            const int row = min(nbase + c, n_nodes - 1);
            const float* xp = x + (size_t)row * IN_DIM;
            bf16x8 A1[4];
            #pragma unroll
            for (int s = 0; s < 4; ++s) {
                const float4 u0 = *(const float4*)(xp + s * 32 + g * 8);
                const float4 u1 = *(const float4*)(xp + s * 32 + g * 8 + 4);
                bf16x8 f;
                f[0] = f2bf(u0.x); f[1] = f2bf(u0.y); f[2] = f2bf(u0.z); f[3] = f2bf(u0.w);
                f[4] = f2bf(u1.x); f[5] = f2bf(u1.y); f[6] = f2bf(u1.z); f[7] = f2bf(u1.w);
                A1[s] = f;
            }

            #pragma unroll
            for (int t = 0; t < 4; ++t) {
                f32x4 acc = {0.f, 0.f, 0.f, 0.f};
                #pragma unroll
                for (int s = 0; s < 4; ++s)
                    acc = __builtin_amdgcn_mfma_f32_16x16x32_bf16(A1[s], B1[s][t], acc, 0, 0, 0);
                #pragma unroll
                for (int r = 0; r < 4; ++r) {
                    const int m = g * 4 + r;
                    const int n = t * 16 + c;
                    const float h0 = gelu_exact(acc[r] + bias[t]);
                    hrow[m * 64 + (n ^ ((m & 7) << 3))] = (ushort)f2bf(h0);
                }
            }
            __syncthreads();

            bf16x8 A2[2];
            #pragma unroll
            for (int s = 0; s < 2; ++s) {
                const int k = s * 32 + g * 8;
                A2[s] = *(const bf16x8*)(hrow + c * 64 + (k ^ ((c & 7) << 3)));
            }

            f32x4 C2[4];
            #pragma unroll
            for (int t = 0; t < 4; ++t) {
                f32x4 acc = {0.f, 0.f, 0.f, 0.f};
                acc = __builtin_amdgcn_mfma_f32_16x16x32_bf16(A2[0], B2[0][t], acc, 0, 0, 0);
                acc = __builtin_amdgcn_mfma_f32_16x16x32_bf16(A2[1], B2[1][t], acc, 0, 0, 0);
                C2[t] = acc;
            }

            float p1v[4] = {0.f, 0.f, 0.f, 0.f}, p2v[4] = {0.f, 0.f, 0.f, 0.f};
            #pragma unroll
            for (int t = 0; t < 4; ++t)
                #pragma unroll
                for (int r = 0; r < 4; ++r) {
                    p1v[r] = fmaf(C2[t][r], a1c[t], p1v[r]);
                    p2v[r] = fmaf(C2[t][r], a2c[t], p2v[r]);
                    const int node = nbase + g * 4 + r;
                    if (node < n_nodes)
                        zb[(size_t)node * OUTD + t * 16 + c] = (ushort)f2bf(C2[t][r]);
                }

            #pragma unroll
            for (int r = 0; r < 4; ++r) {
                p1v[r] += __shfl_xor(p1v[r], 1, 64);
                p1v[r] += __shfl_xor(p1v[r], 2, 64);
                p1v[r] += __shfl_xor(p1v[r], 4, 64);
                p1v[r] += __shfl_xor(p1v[r], 8, 64);
                p2v[r] += __shfl_xor(p2v[r], 1, 64);
                p2v[r] += __shfl_xor(p2v[r], 2, 64);
                p2v[r] += __shfl_xor(p2v[r], 4, 64);
                p2v[r] += __shfl_xor(p2v[r], 8, 64);
            }
            const float v1 = (c == 0) ? p1v[0] : (c == 1) ? p1v[1] : (c == 2) ? p1v[2] : p1v[3];
            const float v2 = (c == 0) ? p2v[0] : (c == 1) ? p2v[1] : (c == 2) ? p2v[2] : p2v[3];
            const int snode = nbase + g * 4 + c;
            if (c < 4 && snode < n_nodes) { s1[snode] = v1; s2[snode] = v2; }
            __syncthreads();
        }
    } else {
        const int bid = blockIdx.x - PROJ_BLOCKS;
        const int lane = tid & 63;
        const int gw = (bid * 256 + tid) >> 6;
        const int nw = (BKT_BLOCKS * 256) >> 6;

        int cnt[NPART];
        #pragma unroll
        for (int p = 0; p < NPART; ++p) cnt[p] = 0;

        const int tiles = (n_edges + 255) >> 8;
        for (int t = gw; t < tiles; t += nw) {
            const int base = (t << 8) + (lane << 2);
            int p0 = -1, p1 = -1, p2 = -1, p3 = -1;
            if (base + 3 < n_edges) {
                const int4 d4 = *(const int4*)(dst + base);
                p0 = d4.x / part_sz; p1 = d4.y / part_sz;
                p2 = d4.z / part_sz; p3 = d4.w / part_sz;
            } else {
                if (base + 0 < n_edges) p0 = dst[base + 0] / part_sz;
                if (base + 1 < n_edges) p1 = dst[base + 1] / part_sz;
                if (base + 2 < n_edges) p2 = dst[base + 2] / part_sz;
                if (base + 3 < n_edges) p3 = dst[base + 3] / part_sz;
            }
            #pragma unroll
            for (int pp = 0; pp < NPART; ++pp) {
                cnt[pp] += __popcll(__ballot(p0 == pp)) + __popcll(__ballot(p1 == pp))
                         + __popcll(__ballot(p2 == pp)) + __popcll(__ballot(p3 == pp));
            }
        }
        if (lane == 0) {
            #pragma unroll
            for (int pp = 0; pp < NPART; ++pp) wcnt[pp * nw + gw] = cnt[pp];
        }
    }
}

// ---------------------------------------------------------------------------
// Level-1 scans, HIERARCHICAL + SEGMENTED (R14-proven: thread t owns a
// contiguous segment -> serial sum -> one block scan -> serial prefix write).
// ---------------------------------------------------------------------------
__global__ __launch_bounds__(256) void k_wtot(
    const int* __restrict__ wcnt, int* __restrict__ tot8, int nw)
{
    __shared__ int buf[256];
    const int p = blockIdx.x, tid = threadIdx.x;
    const int seg = (nw + 255) >> 8;
    const int s0 = tid * seg, s1e = min(s0 + seg, nw);
    int s = 0;
    for (int i = s0; i < s1e; ++i) s += wcnt[p * nw + i];
    buf[tid] = s;
    __syncthreads();
    #pragma unroll
    for (int off = 128; off; off >>= 1) {
        if (tid < off) buf[tid] += buf[tid + off];
        __syncthreads();
    }
    if (tid == 0) tot8[p] = buf[0];
}

__global__ __launch_bounds__(256) void k_wscan(
    int* __restrict__ wcnt, const int* __restrict__ tot8,
    int* __restrict__ off8, int nw)
{
    __shared__ int buf[256];
    const int p = blockIdx.x, tid = threadIdx.x;
    int running = 0;
    for (int q = 0; q < p; ++q) running += tot8[q];
    if (tid == 0) off8[p] = running;

    const int seg = (nw + 255) >> 8;
    const int s0 = tid * seg, s1e = min(s0 + seg, nw);
    int tsum = 0;
    for (int i = s0; i < s1e; ++i) tsum += wcnt[p * nw + i];
    buf[tid] = tsum;
    __syncthreads();
    #pragma unroll
    for (int off = 1; off < 256; off <<= 1) {
        int t = (tid >= off) ? buf[tid - off] : 0;
        __syncthreads();
        buf[tid] += t;
        __syncthreads();
    }
    int prefix = running + buf[tid] - tsum;
    for (int i = s0; i < s1e; ++i) {
        const int v = wcnt[p * nw + i];
        wcnt[p * nw + i] = prefix;
        prefix += v;
    }
}

__global__ __launch_bounds__(256) void k_bwrite(
    const int* __restrict__ src, const int* __restrict__ dst,
    const int* __restrict__ wbase, unsigned* __restrict__ bkt,
    int n_edges, int part_sz)
{
    const int lane = threadIdx.x & 63;
    const int gw = (blockIdx.x * 256 + threadIdx.x) >> 6;
    const int nw = (gridDim.x * 256) >> 6;
    const unsigned long long below = (lane == 63) ? 0x7FFFFFFFFFFFFFFFull
                                                  : ((1ull << lane) - 1ull);

    int base8[NPART];
    #pragma unroll
    for (int pp = 0; pp < NPART; ++pp) base8[pp] = wbase[pp * nw + gw];

    const int tiles = (n_edges + 255) >> 8;
    for (int t = gw; t < tiles; t += nw) {
        const int base = (t << 8) + (lane << 2);
        int p[4]; unsigned pk[4];
        if (base + 3 < n_edges) {
            const int4 d4 = *(const int4*)(dst + base);
            const int4 s4 = *(const int4*)(src + base);
            p[0] = d4.x / part_sz; pk[0] = ((unsigned)(d4.x - p[0] * part_sz) << 17) | (unsigned)s4.x;
            p[1] = d4.y / part_sz; pk[1] = ((unsigned)(d4.y - p[1] * part_sz) << 17) | (unsigned)s4.y;
            p[2] = d4.z / part_sz; pk[2] = ((unsigned)(d4.z - p[2] * part_sz) << 17) | (unsigned)s4.z;
            p[3] = d4.w / part_sz; pk[3] = ((unsigned)(d4.w - p[3] * part_sz) << 17) | (unsigned)s4.w;
        } else {
            #pragma unroll
            for (int j = 0; j < 4; ++j) {
                if (base + j < n_edges) {
                    const int d = dst[base + j];
                    p[j] = d / part_sz;
                    pk[j] = ((unsigned)(d - p[j] * part_sz) << 17) | (unsigned)src[base + j];
                } else p[j] = -1;
            }
        }
        #pragma unroll
        for (int pp = 0; pp < NPART; ++pp) {
            const unsigned long long m0 = __ballot(p[0] == pp);
            const unsigned long long m1 = __ballot(p[1] == pp);
            const unsigned long long m2 = __ballot(p[2] == pp);
            const unsigned long long m3 = __ballot(p[3] == pp);
            const int k0 = __popcll(m0), k1 = __popcll(m1);
            const int k2 = __popcll(m2), k3 = __popcll(m3);
            const int go = base8[pp];
            if ((m0 >> lane) & 1) bkt[go + __popcll(m0 & below)] = pk[0];
            if ((m1 >> lane) & 1) bkt[go + k0 + __popcll(m1 & below)] = pk[1];
            if ((m2 >> lane) & 1) bkt[go + k0 + k1 + __popcll(m2 & below)] = pk[2];
            if ((m3 >> lane) & 1) bkt[go + k0 + k1 + k2 + __popcll(m3 & below)] = pk[3];
            base8[pp] = go + k0 + k1 + k2 + k3;
        }
    }
}

// ---------------------------------------------------------------------------
// LEVEL-2: sub-bucket split; sub = pk>>24 (dst_local>>7): 128-node windows.
// bkt2 uses STATIC per-(p,sub) slots of CAP entries (R16-proven; no off scan).
// ---------------------------------------------------------------------------
__global__ __launch_bounds__(256) void k_scount(
    const unsigned* __restrict__ bkt, const int* __restrict__ tot8,
    const int* __restrict__ off8, int* __restrict__ wcnt2, int nsub)
{
    __shared__ int lcnt[4][SUBW];
    const int p = blockIdx.x & (NPART - 1);
    const int wv = threadIdx.x >> 6, lane = threadIdx.x & 63;
    const int w2 = (blockIdx.x >> 3) * 4 + wv;

    for (int i = lane; i < nsub; i += 64) lcnt[wv][i] = 0;

    const int nB = tot8[p];
    const unsigned* b = bkt + off8[p];
    const int nt = (nB + 255) >> 8;
    for (int t = w2; t < nt; t += 256) {
        const int base = (t << 8) + (lane << 2);
        if (base + 3 < nB) {
            const uint4 v = *(const uint4*)(b + base);
            atomicAdd(&lcnt[wv][v.x >> 24], 1);
            atomicAdd(&lcnt[wv][v.y >> 24], 1);
            atomicAdd(&lcnt[wv][v.z >> 24], 1);
            atomicAdd(&lcnt[wv][v.w >> 24], 1);
        } else {
            for (int j = 0; j < 4; ++j)
                if (base + j < nB) atomicAdd(&lcnt[wv][b[base + j] >> 24], 1);
        }
    }
    for (int i = lane; i < nsub; i += 64)
        wcnt2[(p * nsub + i) * 256 + w2] = lcnt[wv][i];
}

__global__ __launch_bounds__(256) void k_sscan(
    int* __restrict__ wcnt2, int* __restrict__ tot2)
{
    __shared__ int buf[256];
    const int ps = blockIdx.x, tid = threadIdx.x;
    const int v = wcnt2[ps * 256 + tid];
    buf[tid] = v;
    __syncthreads();
    #pragma unroll
    for (int off = 1; off < 256; off <<= 1) {
        int t = (tid >= off) ? buf[tid - off] : 0;
        __syncthreads();
        buf[tid] += t;
        __syncthreads();
    }
    wcnt2[ps * 256 + tid] = buf[tid] - v;   // exclusive within sub-bucket
    if (tid == 255) tot2[ps] = buf[255];
}

__global__ __launch_bounds__(256) void k_swrite(
    const unsigned* __restrict__ bkt, const int* __restrict__ tot8,
    const int* __restrict__ off8, const int* __restrict__ wcnt2,
    unsigned* __restrict__ bkt2, int nsub)
{
    __shared__ int lbase[4][SUBW];
    const int p = blockIdx.x & (NPART - 1);
    const int wv = threadIdx.x >> 6, lane = threadIdx.x & 63;
    const int w2 = (blockIdx.x >> 3) * 4 + wv;

    for (int i = lane; i < nsub; i += 64)
        lbase[wv][i] = (p * nsub + i) * CAP + wcnt2[(p * nsub + i) * 256 + w2];

    const int nB = tot8[p];
    const unsigned* b = bkt + off8[p];
    const int nt = (nB + 255) >> 8;
    for (int t = w2; t < nt; t += 256) {
        const int base = (t << 8) + (lane << 2);
        if (base + 3 < nB) {
            const uint4 v = *(const uint4*)(b + base);
            bkt2[atomicAdd(&lbase[wv][v.x >> 24], 1)] = v.x;
            bkt2[atomicAdd(&lbase[wv][v.y >> 24], 1)] = v.y;
            bkt2[atomicAdd(&lbase[wv][v.z >> 24], 1)] = v.z;
            bkt2[atomicAdd(&lbase[wv][v.w >> 24], 1)] = v.w;
        } else {
            for (int j = 0; j < 4; ++j)
                if (base + j < nB) {
                    const unsigned pk = b[base + j];
                    bkt2[atomicAdd(&lbase[wv][pk >> 24], 1)] = pk;
                }
        }
    }
}

// ---------------------------------------------------------------------------
// SORTED AGG (R14-proven: SUBW=128, 512 threads): counting sort in LDS with
// q precomputed; uniform-address reads; unroll-8; register racc/rden.
// ---------------------------------------------------------------------------
__global__ __launch_bounds__(512) void k_sorted_agg(
    const unsigned* __restrict__ bkt2, const int* __restrict__ tot2,
    const float* __restrict__ s1, const float* __restrict__ s2,
    const ushort* __restrict__ zb, float* __restrict__ h,
    int n_nodes, int part_sz, int nsub)
{
    __shared__ uint2 sorted[CAP];      // 24 KB
    __shared__ int cnt[SUBW];
    __shared__ int scn[SUBW];
    __shared__ int cur[SUBW];

    const int p = blockIdx.x & (NPART - 1);
    const int sub = blockIdx.x >> 3;
    const int ps = p * nsub + sub;
    const int pbase = p * part_sz;
    const int wbase = sub * SUBW;
    const int psz = min(part_sz, n_nodes - pbase);
    const int wn = min(SUBW, psz - wbase);
    if (wn <= 0) return;

    const int tid = threadIdx.x, wv = tid >> 6, lane = tid & 63;

    if (tid < SUBW) cnt[tid] = 0;
    __syncthreads();

    int n2 = tot2[ps];
    if (n2 > CAP) n2 = CAP;   // defensive; mean 2041, sigma 45
    const unsigned* b = bkt2 + (size_t)ps * CAP;

    for (int i = tid; i < n2; i += 512)
        atomicAdd(&cnt[(b[i] >> 17) & (SUBW - 1)], 1);
    __syncthreads();

    if (tid < SUBW) scn[tid] = cnt[tid];
    __syncthreads();
    #pragma unroll
    for (int off = 1; off < SUBW; off <<= 1) {
        int t = 0;
        if (tid < SUBW && tid >= off) t = scn[tid - off];
        __syncthreads();
        if (tid < SUBW) scn[tid] += t;
        __syncthreads();
    }
    if (tid < SUBW) cur[tid] = scn[tid] - cnt[tid];
    __syncthreads();

    for (int i = tid; i < n2; i += 512) {
        const unsigned pk = b[i];
        const int sv = (int)(pk & 0x1FFFFu);
        const int dfull = (int)(pk >> 17);
        float e = s1[sv] + s2[pbase + dfull];
        e = e > 0.f ? e : 0.01f * e;
        const float q = __expf(e);
        const int pos = atomicAdd(&cur[dfull & (SUBW - 1)], 1);
        sorted[pos] = make_uint2(pk, __float_as_uint(q));
    }
    __syncthreads();

    // wave wv owns window-local nodes [nlo, nhi): 16 nodes per wave
    const int nlo = wv * 16;
    const int nhi = nlo + 16;
    const int lo = (nlo == 0) ? 0 : scn[nlo - 1];
    const int hi = scn[nhi - 1];

    float racc = 0.f, rden = 0.f;
    int curd = -1;
    int lastw = nlo - 1;

#define FLUSH() do { if (curd >= 0) { \
        for (int z_ = lastw + 1; z_ < curd; ++z_) \
            h[(size_t)(pbase + wbase + z_) * OUTD + lane] = 0.f; \
        h[(size_t)(pbase + wbase + curd) * OUTD + lane] = racc / fmaxf(rden, 1e-9f); \
        lastw = curd; } } while (0)

#define STEP2(D, Q, Z) do { \
        if ((D) != curd) { FLUSH(); curd = (D); racc = 0.f; rden = 0.f; } \
        racc = fmaf((Q), (Z), racc); rden += (Q); } while (0)

    int e = lo;
    for (; e + 7 < hi; e += 8) {
        const uint2 u0 = sorted[e + 0], u1 = sorted[e + 1];
        const uint2 u2 = sorted[e + 2], u3 = sorted[e + 3];
        const uint2 u4 = sorted[e + 4], u5 = sorted[e + 5];
        const uint2 u6 = sorted[e + 6], u7 = sorted[e + 7];
        const float z0 = bf2f(zb[(size_t)(u0.x & 0x1FFFFu) * OUTD + lane]);
        const float z1 = bf2f(zb[(size_t)(u1.x & 0x1FFFFu) * OUTD + lane]);
        const float z2 = bf2f(zb[(size_t)(u2.x & 0x1FFFFu) * OUTD + lane]);
        const float z3 = bf2f(zb[(size_t)(u3.x & 0x1FFFFu) * OUTD + lane]);
        const float z4 = bf2f(zb[(size_t)(u4.x & 0x1FFFFu) * OUTD + lane]);
        const float z5 = bf2f(zb[(size_t)(u5.x & 0x1FFFFu) * OUTD + lane]);
        const float z6 = bf2f(zb[(size_t)(u6.x & 0x1FFFFu) * OUTD + lane]);
        const float z7 = bf2f(zb[(size_t)(u7.x & 0x1FFFFu) * OUTD + lane]);
        STEP2((int)((u0.x >> 17) & (SUBW - 1)), __uint_as_float(u0.y), z0);
        STEP2((int)((u1.x >> 17) & (SUBW - 1)), __uint_as_float(u1.y), z1);
        STEP2((int)((u2.x >> 17) & (SUBW - 1)), __uint_as_float(u2.y), z2);
        STEP2((int)((u3.x >> 17) & (SUBW - 1)), __uint_as_float(u3.y), z3);
        STEP2((int)((u4.x >> 17) & (SUBW - 1)), __uint_as_float(u4.y), z4);
        STEP2((int)((u5.x >> 17) & (SUBW - 1)), __uint_as_float(u5.y), z5);
        STEP2((int)((u6.x >> 17) & (SUBW - 1)), __uint_as_float(u6.y), z6);
        STEP2((int)((u7.x >> 17) & (SUBW - 1)), __uint_as_float(u7.y), z7);
    }
    for (; e < hi; ++e) {
        const uint2 u = sorted[e];
        const float z = bf2f(zb[(size_t)(u.x & 0x1FFFFu) * OUTD + lane]);
        STEP2((int)((u.x >> 17) & (SUBW - 1)), __uint_as_float(u.y), z);
    }
    FLUSH();
    const int zend = min(nhi, wn);
    for (int z = lastw + 1; z < zend; ++z)
        h[(size_t)(pbase + wbase + z) * OUTD + lane] = 0.f;
#undef STEP2
#undef FLUSH
}

extern "C" void kernel_launch(void* const* d_in, const int* in_sizes, int n_in,
                              void* d_out, int out_size, void* d_ws, size_t ws_size,
                              hipStream_t stream)
{
    const float* x    = (const float*)d_in[0];
    const float* w_in = (const float*)d_in[1];
    const float* b_in = (const float*)d_in[2];
    const float* w    = (const float*)d_in[3];
    const float* a    = (const float*)d_in[4];
    const int*   src  = (const int*)d_in[5];
    const int*   dst  = (const int*)d_in[6];
    const int n_nodes = in_sizes[0] / IN_DIM;
    const int n_edges = in_sizes[5];

    float* h = (float*)d_out;

    const int NW = BKT_BLOCKS * 4;
    const int part_sz = (n_nodes + NPART - 1) / NPART;
    const int nsub = (part_sz + SUBW - 1) / SUBW;  // 98 for n=100000
    const int nps = NPART * nsub;

    // workspace (~31 MB): zb | s1 | s2 | tot8/off8 | wcnt | wcnt2 | tot2 | bkt | bkt2
    ushort*   zb    = (ushort*)d_ws;                      // n_nodes*64 bf16
    float*    s1    = (float*)(zb + (size_t)n_nodes * OUTD);
    float*    s2    = s1 + n_nodes;
    int*      tot8  = (int*)(s2 + n_nodes);               // 8
    int*      off8  = tot8 + NPART;                       // 9 (region padded to 64)
    int*      wcnt  = tot8 + 64;                          // 8*NW
    int*      wcnt2 = wcnt + NPART * NW;                  // 8*128*256
    int*      tot2  = wcnt2 + NPART * 128 * 256;          // 8*128
    unsigned* bkt   = (unsigned*)(tot2 + NPART * 128);    // n_edges
    unsigned* bkt2  = bkt + n_edges;                      // nps*CAP (9.6 MB)

    const int ntiles = (n_nodes + 63) / 64;

    k_proj_bcount<<<PROJ_BLOCKS + BKT_BLOCKS, 256, 0, stream>>>(
        x, w_in, b_in, w, a, zb, s1, s2, dst, wcnt,
        n_nodes, ntiles, n_edges, part_sz);

    k_wtot<<<NPART, 256, 0, stream>>>(wcnt, tot8, NW);
    k_wscan<<<NPART, 256, 0, stream>>>(wcnt, tot8, off8, NW);
    k_bwrite<<<BKT_BLOCKS, 256, 0, stream>>>(src, dst, wcnt, bkt, n_edges, part_sz);

    k_scount<<<L2_BLOCKS, 256, 0, stream>>>(bkt, tot8, off8, wcnt2, nsub);
    k_sscan<<<nps, 256, 0, stream>>>(wcnt2, tot2);
    k_swrite<<<L2_BLOCKS, 256, 0, stream>>>(bkt, tot8, off8, wcnt2, bkt2, nsub);

    k_sorted_agg<<<nps, 512, 0, stream>>>(bkt2, tot2, s1, s2, zb,
                                          h, n_nodes, part_sz, nsub);
}

// Round 18
// 114.469 us; speedup vs baseline: 1.1182x; 1.0241x over previous
//
#include <hip/hip_runtime.h>
#include <hip/hip_bf16.h>

#define IN_DIM 128
#define HID    64
#define OUTD   64
#define NPART  8
#define SUBW   64            // nodes per level-2 window (power of 2)
#define CAP    1536          // fixed sorted-edge slot per (p,sub); mean 1020 sigma 32
#define MAXNSUB 200
#define NW2    128           // level-2 waves per partition
#define PROJ_BLOCKS 1043
#define BKT_BLOCKS 1024      // level-1 radix: NW = 4096 waves
#define L2_BLOCKS 256        // 32 blocks/partition * 4 waves = NW2

typedef __attribute__((ext_vector_type(8))) short bf16x8;
typedef __attribute__((ext_vector_type(4))) float f32x4;

__device__ __forceinline__ float gelu_exact(float v) {
    return v * 0.5f * (1.0f + erff(v * 0.70710678118654752f));
}
__device__ __forceinline__ short f2bf(float f) {
    __hip_bfloat16 b = __float2bfloat16(f);   // RNE
    return *reinterpret_cast<short*>(&b);
}
__device__ __forceinline__ float bf2f(ushort u) {
    return __uint_as_float(((unsigned)u) << 16);
}

// ---------------------------------------------------------------------------
// FUSED K1: blocks [0,PROJ_BLOCKS) = MFMA node projection; rest = level-1
// count (ballot, no atomics). Independent -> concurrent. (R17-proven)
// ---------------------------------------------------------------------------
__global__ __launch_bounds__(256) void k_proj_bcount(
    const float* __restrict__ x, const float* __restrict__ w_in,
    const float* __restrict__ b_in, const float* __restrict__ w,
    const float* __restrict__ a,
    ushort* __restrict__ zb, float* __restrict__ s1, float* __restrict__ s2,
    const int* __restrict__ dst, int* __restrict__ wcnt,
    int n_nodes, int ntiles, int n_edges, int part_sz)
{
    __shared__ ushort h0s[4][16 * 64];

    const int tid = threadIdx.x;

    if (blockIdx.x < PROJ_BLOCKS) {
        const int wv = tid >> 6, l = tid & 63;
        const int c = l & 15, g = l >> 4;

        bf16x8 B1[4][4];
        #pragma unroll
        for (int s = 0; s < 4; ++s)
            #pragma unroll
            for (int t = 0; t < 4; ++t) {
                bf16x8 f;
                #pragma unroll
                for (int e = 0; e < 8; ++e)
                    f[e] = f2bf(w_in[(s * 32 + g * 8 + e) * HID + t * 16 + c]);
                B1[s][t] = f;
            }
        bf16x8 B2[2][4];
        #pragma unroll
        for (int s = 0; s < 2; ++s)
            #pragma unroll
            for (int t = 0; t < 4; ++t) {
                bf16x8 f;
                #pragma unroll
                for (int e = 0; e < 8; ++e)
                    f[e] = f2bf(w[(s * 32 + g * 8 + e) * OUTD + t * 16 + c]);
                B2[s][t] = f;
            }
        float bias[4], a1c[4], a2c[4];
        #pragma unroll
        for (int t = 0; t < 4; ++t) {
            bias[t] = b_in[t * 16 + c];
            a1c[t]  = a[t * 16 + c];
            a2c[t]  = a[OUTD + t * 16 + c];
        }

        ushort* hrow = &h0s[wv][0];

        for (int tile = blockIdx.x; tile < ntiles; tile += PROJ_BLOCKS) {
            const int nbase = tile * 64 + wv * 16;

            const int row = min(nbase + c, n_nodes - 1);
            const float* xp = x + (size_t)row * IN_DIM;
            bf16x8 A1[4];
            #pragma unroll
            for (int s = 0; s < 4; ++s) {
                const float4 u0 = *(const float4*)(xp + s * 32 + g * 8);
                const float4 u1 = *(const float4*)(xp + s * 32 + g * 8 + 4);
                bf16x8 f;
                f[0] = f2bf(u0.x); f[1] = f2bf(u0.y); f[2] = f2bf(u0.z); f[3] = f2bf(u0.w);
                f[4] = f2bf(u1.x); f[5] = f2bf(u1.y); f[6] = f2bf(u1.z); f[7] = f2bf(u1.w);
                A1[s] = f;
            }

            #pragma unroll
            for (int t = 0; t < 4; ++t) {
                f32x4 acc = {0.f, 0.f, 0.f, 0.f};
                #pragma unroll
                for (int s = 0; s < 4; ++s)
                    acc = __builtin_amdgcn_mfma_f32_16x16x32_bf16(A1[s], B1[s][t], acc, 0, 0, 0);
                #pragma unroll
                for (int r = 0; r < 4; ++r) {
                    const int m = g * 4 + r;
                    const int n = t * 16 + c;
                    const float h0 = gelu_exact(acc[r] + bias[t]);
                    hrow[m * 64 + (n ^ ((m & 7) << 3))] = (ushort)f2bf(h0);
                }
            }
            __syncthreads();

            bf16x8 A2[2];
            #pragma unroll
            for (int s = 0; s < 2; ++s) {
                const int k = s * 32 + g * 8;
                A2[s] = *(const bf16x8*)(hrow + c * 64 + (k ^ ((c & 7) << 3)));
            }

            f32x4 C2[4];
            #pragma unroll
            for (int t = 0; t < 4; ++t) {
                f32x4 acc = {0.f, 0.f, 0.f, 0.f};
                acc = __builtin_amdgcn_mfma_f32_16x16x32_bf16(A2[0], B2[0][t], acc, 0, 0, 0);
                acc = __builtin_amdgcn_mfma_f32_16x16x32_bf16(A2[1], B2[1][t], acc, 0, 0, 0);
                C2[t] = acc;
            }

            float p1v[4] = {0.f, 0.f, 0.f, 0.f}, p2v[4] = {0.f, 0.f, 0.f, 0.f};
            #pragma unroll
            for (int t = 0; t < 4; ++t)
                #pragma unroll
                for (int r = 0; r < 4; ++r) {
                    p1v[r] = fmaf(C2[t][r], a1c[t], p1v[r]);
                    p2v[r] = fmaf(C2[t][r], a2c[t], p2v[r]);
                    const int node = nbase + g * 4 + r;
                    if (node < n_nodes)
                        zb[(size_t)node * OUTD + t * 16 + c] = (ushort)f2bf(C2[t][r]);
                }

            #pragma unroll
            for (int r = 0; r < 4; ++r) {
                p1v[r] += __shfl_xor(p1v[r], 1, 64);
                p1v[r] += __shfl_xor(p1v[r], 2, 64);
                p1v[r] += __shfl_xor(p1v[r], 4, 64);
                p1v[r] += __shfl_xor(p1v[r], 8, 64);
                p2v[r] += __shfl_xor(p2v[r], 1, 64);
                p2v[r] += __shfl_xor(p2v[r], 2, 64);
                p2v[r] += __shfl_xor(p2v[r], 4, 64);
                p2v[r] += __shfl_xor(p2v[r], 8, 64);
            }
            const float v1 = (c == 0) ? p1v[0] : (c == 1) ? p1v[1] : (c == 2) ? p1v[2] : p1v[3];
            const float v2 = (c == 0) ? p2v[0] : (c == 1) ? p2v[1] : (c == 2) ? p2v[2] : p2v[3];
            const int snode = nbase + g * 4 + c;
            if (c < 4 && snode < n_nodes) { s1[snode] = v1; s2[snode] = v2; }
            __syncthreads();
        }
    } else {
        const int bid = blockIdx.x - PROJ_BLOCKS;
        const int lane = tid & 63;
        const int gw = (bid * 256 + tid) >> 6;
        const int nw = (BKT_BLOCKS * 256) >> 6;

        int cnt[NPART];
        #pragma unroll
        for (int p = 0; p < NPART; ++p) cnt[p] = 0;

        const int tiles = (n_edges + 255) >> 8;
        for (int t = gw; t < tiles; t += nw) {
            const int base = (t << 8) + (lane << 2);
            int p0 = -1, p1 = -1, p2 = -1, p3 = -1;
            if (base + 3 < n_edges) {
                const int4 d4 = *(const int4*)(dst + base);
                p0 = d4.x / part_sz; p1 = d4.y / part_sz;
                p2 = d4.z / part_sz; p3 = d4.w / part_sz;
            } else {
                if (base + 0 < n_edges) p0 = dst[base + 0] / part_sz;
                if (base + 1 < n_edges) p1 = dst[base + 1] / part_sz;
                if (base + 2 < n_edges) p2 = dst[base + 2] / part_sz;
                if (base + 3 < n_edges) p3 = dst[base + 3] / part_sz;
            }
            #pragma unroll
            for (int pp = 0; pp < NPART; ++pp) {
                cnt[pp] += __popcll(__ballot(p0 == pp)) + __popcll(__ballot(p1 == pp))
                         + __popcll(__ballot(p2 == pp)) + __popcll(__ballot(p3 == pp));
            }
        }
        if (lane == 0) {
            #pragma unroll
            for (int pp = 0; pp < NPART; ++pp) wcnt[pp * nw + gw] = cnt[pp];
        }
    }
}

// ---------------------------------------------------------------------------
// Level-1 scans, hierarchical + segmented (R14/R17-proven).
// ---------------------------------------------------------------------------
__global__ __launch_bounds__(256) void k_wtot(
    const int* __restrict__ wcnt, int* __restrict__ tot8, int nw)
{
    __shared__ int buf[256];
    const int p = blockIdx.x, tid = threadIdx.x;
    const int seg = (nw + 255) >> 8;
    const int s0 = tid * seg, s1e = min(s0 + seg, nw);
    int s = 0;
    for (int i = s0; i < s1e; ++i) s += wcnt[p * nw + i];
    buf[tid] = s;
    __syncthreads();
    #pragma unroll
    for (int off = 128; off; off >>= 1) {
        if (tid < off) buf[tid] += buf[tid + off];
        __syncthreads();
    }
    if (tid == 0) tot8[p] = buf[0];
}

__global__ __launch_bounds__(256) void k_wscan(
    int* __restrict__ wcnt, const int* __restrict__ tot8,
    int* __restrict__ off8, int nw)
{
    __shared__ int buf[256];
    const int p = blockIdx.x, tid = threadIdx.x;
    int running = 0;
    for (int q = 0; q < p; ++q) running += tot8[q];
    if (tid == 0) off8[p] = running;

    const int seg = (nw + 255) >> 8;
    const int s0 = tid * seg, s1e = min(s0 + seg, nw);
    int tsum = 0;
    for (int i = s0; i < s1e; ++i) tsum += wcnt[p * nw + i];
    buf[tid] = tsum;
    __syncthreads();
    #pragma unroll
    for (int off = 1; off < 256; off <<= 1) {
        int t = (tid >= off) ? buf[tid - off] : 0;
        __syncthreads();
        buf[tid] += t;
        __syncthreads();
    }
    int prefix = running + buf[tid] - tsum;
    for (int i = s0; i < s1e; ++i) {
        const int v = wcnt[p * nw + i];
        wcnt[p * nw + i] = prefix;
        prefix += v;
    }
}

__global__ __launch_bounds__(256) void k_bwrite(
    const int* __restrict__ src, const int* __restrict__ dst,
    const int* __restrict__ wbase, unsigned* __restrict__ bkt,
    int n_edges, int part_sz)
{
    const int lane = threadIdx.x & 63;
    const int gw = (blockIdx.x * 256 + threadIdx.x) >> 6;
    const int nw = (gridDim.x * 256) >> 6;
    const unsigned long long below = (lane == 63) ? 0x7FFFFFFFFFFFFFFFull
                                                  : ((1ull << lane) - 1ull);

    int base8[NPART];
    #pragma unroll
    for (int pp = 0; pp < NPART; ++pp) base8[pp] = wbase[pp * nw + gw];

    const int tiles = (n_edges + 255) >> 8;
    for (int t = gw; t < tiles; t += nw) {
        const int base = (t << 8) + (lane << 2);
        int p[4]; unsigned pk[4];
        if (base + 3 < n_edges) {
            const int4 d4 = *(const int4*)(dst + base);
            const int4 s4 = *(const int4*)(src + base);
            p[0] = d4.x / part_sz; pk[0] = ((unsigned)(d4.x - p[0] * part_sz) << 17) | (unsigned)s4.x;
            p[1] = d4.y / part_sz; pk[1] = ((unsigned)(d4.y - p[1] * part_sz) << 17) | (unsigned)s4.y;
            p[2] = d4.z / part_sz; pk[2] = ((unsigned)(d4.z - p[2] * part_sz) << 17) | (unsigned)s4.z;
            p[3] = d4.w / part_sz; pk[3] = ((unsigned)(d4.w - p[3] * part_sz) << 17) | (unsigned)s4.w;
        } else {
            #pragma unroll
            for (int j = 0; j < 4; ++j) {
                if (base + j < n_edges) {
                    const int d = dst[base + j];
                    p[j] = d / part_sz;
                    pk[j] = ((unsigned)(d - p[j] * part_sz) << 17) | (unsigned)src[base + j];
                } else p[j] = -1;
            }
        }
        #pragma unroll
        for (int pp = 0; pp < NPART; ++pp) {
            const unsigned long long m0 = __ballot(p[0] == pp);
            const unsigned long long m1 = __ballot(p[1] == pp);
            const unsigned long long m2 = __ballot(p[2] == pp);
            const unsigned long long m3 = __ballot(p[3] == pp);
            const int k0 = __popcll(m0), k1 = __popcll(m1);
            const int k2 = __popcll(m2), k3 = __popcll(m3);
            const int go = base8[pp];
            if ((m0 >> lane) & 1) bkt[go + __popcll(m0 & below)] = pk[0];
            if ((m1 >> lane) & 1) bkt[go + k0 + __popcll(m1 & below)] = pk[1];
            if ((m2 >> lane) & 1) bkt[go + k0 + k1 + __popcll(m2 & below)] = pk[2];
            if ((m3 >> lane) & 1) bkt[go + k0 + k1 + k2 + __popcll(m3 & below)] = pk[3];
            base8[pp] = go + k0 + k1 + k2 + k3;
        }
    }
}

// ---------------------------------------------------------------------------
// LEVEL-2: sub-bucket split; sub = pk>>23 (dst_local>>6): 64-node windows.
// NW2=128 waves/partition (halves wcnt2 vs R15). Static-CAP bkt2 slots.
// ---------------------------------------------------------------------------
__global__ __launch_bounds__(256) void k_scount(
    const unsigned* __restrict__ bkt, const int* __restrict__ tot8,
    const int* __restrict__ off8, int* __restrict__ wcnt2, int nsub)
{
    __shared__ int lcnt[4][MAXNSUB];
    const int p = blockIdx.x & (NPART - 1);
    const int wv = threadIdx.x >> 6, lane = threadIdx.x & 63;
    const int w2 = (blockIdx.x >> 3) * 4 + wv;          // 0..NW2-1

    for (int i = lane; i < nsub; i += 64) lcnt[wv][i] = 0;

    const int nB = tot8[p];
    const unsigned* b = bkt + off8[p];
    const int nt = (nB + 255) >> 8;
    for (int t = w2; t < nt; t += NW2) {
        const int base = (t << 8) + (lane << 2);
        if (base + 3 < nB) {
            const uint4 v = *(const uint4*)(b + base);
            atomicAdd(&lcnt[wv][v.x >> 23], 1);
            atomicAdd(&lcnt[wv][v.y >> 23], 1);
            atomicAdd(&lcnt[wv][v.z >> 23], 1);
            atomicAdd(&lcnt[wv][v.w >> 23], 1);
        } else {
            for (int j = 0; j < 4; ++j)
                if (base + j < nB) atomicAdd(&lcnt[wv][b[base + j] >> 23], 1);
        }
    }
    for (int i = lane; i < nsub; i += 64)
        wcnt2[(p * nsub + i) * NW2 + w2] = lcnt[wv][i];
}

__global__ __launch_bounds__(128) void k_sscan(
    int* __restrict__ wcnt2, int* __restrict__ tot2)
{
    __shared__ int buf[NW2];
    const int ps = blockIdx.x, tid = threadIdx.x;
    const int v = wcnt2[ps * NW2 + tid];
    buf[tid] = v;
    __syncthreads();
    #pragma unroll
    for (int off = 1; off < NW2; off <<= 1) {
        int t = (tid >= off) ? buf[tid - off] : 0;
        __syncthreads();
        buf[tid] += t;
        __syncthreads();
    }
    wcnt2[ps * NW2 + tid] = buf[tid] - v;   // exclusive within sub-bucket
    if (tid == NW2 - 1) tot2[ps] = buf[NW2 - 1];
}

__global__ __launch_bounds__(256) void k_swrite(
    const unsigned* __restrict__ bkt, const int* __restrict__ tot8,
    const int* __restrict__ off8, const int* __restrict__ wcnt2,
    unsigned* __restrict__ bkt2, int nsub)
{
    __shared__ int lbase[4][MAXNSUB];
    const int p = blockIdx.x & (NPART - 1);
    const int wv = threadIdx.x >> 6, lane = threadIdx.x & 63;
    const int w2 = (blockIdx.x >> 3) * 4 + wv;

    for (int i = lane; i < nsub; i += 64)
        lbase[wv][i] = (p * nsub + i) * CAP + wcnt2[(p * nsub + i) * NW2 + w2];

    const int nB = tot8[p];
    const unsigned* b = bkt + off8[p];
    const int nt = (nB + 255) >> 8;
    for (int t = w2; t < nt; t += NW2) {
        const int base = (t << 8) + (lane << 2);
        if (base + 3 < nB) {
            const uint4 v = *(const uint4*)(b + base);
            bkt2[atomicAdd(&lbase[wv][v.x >> 23], 1)] = v.x;
            bkt2[atomicAdd(&lbase[wv][v.y >> 23], 1)] = v.y;
            bkt2[atomicAdd(&lbase[wv][v.z >> 23], 1)] = v.z;
            bkt2[atomicAdd(&lbase[wv][v.w >> 23], 1)] = v.w;
        } else {
            for (int j = 0; j < 4; ++j)
                if (base + j < nB) {
                    const unsigned pk = b[base + j];
                    bkt2[atomicAdd(&lbase[wv][pk >> 23], 1)] = pk;
                }
        }
    }
}

// ---------------------------------------------------------------------------
// SORTED AGG (SUBW=64, R15-measured 51.9us at occ 55%): counting sort in LDS
// with q precomputed; uniform-address reads; unroll-8; register racc/rden.
// ---------------------------------------------------------------------------
__global__ __launch_bounds__(512) void k_sorted_agg(
    const unsigned* __restrict__ bkt2, const int* __restrict__ tot2,
    const float* __restrict__ s1, const float* __restrict__ s2,
    const ushort* __restrict__ zb, float* __restrict__ h,
    int n_nodes, int part_sz, int nsub)
{
    __shared__ uint2 sorted[CAP];      // 12 KB
    __shared__ int cnt[SUBW];
    __shared__ int scn[SUBW];
    __shared__ int cur[SUBW];

    const int p = blockIdx.x & (NPART - 1);
    const int sub = blockIdx.x >> 3;
    const int ps = p * nsub + sub;
    const int pbase = p * part_sz;
    const int wbase = sub * SUBW;
    const int psz = min(part_sz, n_nodes - pbase);
    const int wn = min(SUBW, psz - wbase);
    if (wn <= 0) return;

    const int tid = threadIdx.x, wv = tid >> 6, lane = tid & 63;

    if (tid < SUBW) cnt[tid] = 0;
    __syncthreads();

    int n2 = tot2[ps];
    if (n2 > CAP) n2 = CAP;   // defensive; mean 1020, sigma 32
    const unsigned* b = bkt2 + (size_t)ps * CAP;

    for (int i = tid; i < n2; i += 512)
        atomicAdd(&cnt[(b[i] >> 17) & (SUBW - 1)], 1);
    __syncthreads();

    if (tid < SUBW) scn[tid] = cnt[tid];
    __syncthreads();
    #pragma unroll
    for (int off = 1; off < SUBW; off <<= 1) {
        int t = 0;
        if (tid < SUBW && tid >= off) t = scn[tid - off];
        __syncthreads();
        if (tid < SUBW) scn[tid] += t;
        __syncthreads();
    }
    if (tid < SUBW) cur[tid] = scn[tid] - cnt[tid];
    __syncthreads();

    for (int i = tid; i < n2; i += 512) {
        const unsigned pk = b[i];
        const int sv = (int)(pk & 0x1FFFFu);
        const int dfull = (int)(pk >> 17);
        float e = s1[sv] + s2[pbase + dfull];
        e = e > 0.f ? e : 0.01f * e;
        const float q = __expf(e);
        const int pos = atomicAdd(&cur[dfull & (SUBW - 1)], 1);
        sorted[pos] = make_uint2(pk, __float_as_uint(q));
    }
    __syncthreads();

    // wave wv owns window-local nodes [nlo, nhi): 8 nodes per wave
    const int nlo = wv * 8;
    const int nhi = nlo + 8;
    const int lo = (nlo == 0) ? 0 : scn[nlo - 1];
    const int hi = scn[nhi - 1];

    float racc = 0.f, rden = 0.f;
    int curd = -1;
    int lastw = nlo - 1;

#define FLUSH() do { if (curd >= 0) { \
        for (int z_ = lastw + 1; z_ < curd; ++z_) \
            h[(size_t)(pbase + wbase + z_) * OUTD + lane] = 0.f; \
        h[(size_t)(pbase + wbase + curd) * OUTD + lane] = racc / fmaxf(rden, 1e-9f); \
        lastw = curd; } } while (0)

#define STEP2(D, Q, Z) do { \
        if ((D) != curd) { FLUSH(); curd = (D); racc = 0.f; rden = 0.f; } \
        racc = fmaf((Q), (Z), racc); rden += (Q); } while (0)

    int e = lo;
    for (; e + 7 < hi; e += 8) {
        const uint2 u0 = sorted[e + 0], u1 = sorted[e + 1];
        const uint2 u2 = sorted[e + 2], u3 = sorted[e + 3];
        const uint2 u4 = sorted[e + 4], u5 = sorted[e + 5];
        const uint2 u6 = sorted[e + 6], u7 = sorted[e + 7];
        const float z0 = bf2f(zb[(size_t)(u0.x & 0x1FFFFu) * OUTD + lane]);
        const float z1 = bf2f(zb[(size_t)(u1.x & 0x1FFFFu) * OUTD + lane]);
        const float z2 = bf2f(zb[(size_t)(u2.x & 0x1FFFFu) * OUTD + lane]);
        const float z3 = bf2f(zb[(size_t)(u3.x & 0x1FFFFu) * OUTD + lane]);
        const float z4 = bf2f(zb[(size_t)(u4.x & 0x1FFFFu) * OUTD + lane]);
        const float z5 = bf2f(zb[(size_t)(u5.x & 0x1FFFFu) * OUTD + lane]);
        const float z6 = bf2f(zb[(size_t)(u6.x & 0x1FFFFu) * OUTD + lane]);
        const float z7 = bf2f(zb[(size_t)(u7.x & 0x1FFFFu) * OUTD + lane]);
        STEP2((int)((u0.x >> 17) & (SUBW - 1)), __uint_as_float(u0.y), z0);
        STEP2((int)((u1.x >> 17) & (SUBW - 1)), __uint_as_float(u1.y), z1);
        STEP2((int)((u2.x >> 17) & (SUBW - 1)), __uint_as_float(u2.y), z2);
        STEP2((int)((u3.x >> 17) & (SUBW - 1)), __uint_as_float(u3.y), z3);
        STEP2((int)((u4.x >> 17) & (SUBW - 1)), __uint_as_float(u4.y), z4);
        STEP2((int)((u5.x >> 17) & (SUBW - 1)), __uint_as_float(u5.y), z5);
        STEP2((int)((u6.x >> 17) & (SUBW - 1)), __uint_as_float(u6.y), z6);
        STEP2((int)((u7.x >> 17) & (SUBW - 1)), __uint_as_float(u7.y), z7);
    }
    for (; e < hi; ++e) {
        const uint2 u = sorted[e];
        const float z = bf2f(zb[(size_t)(u.x & 0x1FFFFu) * OUTD + lane]);
        STEP2((int)((u.x >> 17) & (SUBW - 1)), __uint_as_float(u.y), z);
    }
    FLUSH();
    const int zend = min(nhi, wn);
    for (int z = lastw + 1; z < zend; ++z)
        h[(size_t)(pbase + wbase + z) * OUTD + lane] = 0.f;
#undef STEP2
#undef FLUSH
}

extern "C" void kernel_launch(void* const* d_in, const int* in_sizes, int n_in,
                              void* d_out, int out_size, void* d_ws, size_t ws_size,
                              hipStream_t stream)
{
    const float* x    = (const float*)d_in[0];
    const float* w_in = (const float*)d_in[1];
    const float* b_in = (const float*)d_in[2];
    const float* w    = (const float*)d_in[3];
    const float* a    = (const float*)d_in[4];
    const int*   src  = (const int*)d_in[5];
    const int*   dst  = (const int*)d_in[6];
    const int n_nodes = in_sizes[0] / IN_DIM;
    const int n_edges = in_sizes[5];

    float* h = (float*)d_out;

    const int NW = BKT_BLOCKS * 4;
    const int part_sz = (n_nodes + NPART - 1) / NPART;
    const int nsub = (part_sz + SUBW - 1) / SUBW;  // 196 <= MAXNSUB
    const int nps = NPART * nsub;

    // workspace (~30 MB): zb | s1 | s2 | tot8/off8 | wcnt | wcnt2 | tot2 | bkt | bkt2
    ushort*   zb    = (ushort*)d_ws;                      // n_nodes*64 bf16
    float*    s1    = (float*)(zb + (size_t)n_nodes * OUTD);
    float*    s2    = s1 + n_nodes;
    int*      tot8  = (int*)(s2 + n_nodes);               // 8
    int*      off8  = tot8 + NPART;                       // 9 (region padded to 64)
    int*      wcnt  = tot8 + 64;                          // 8*NW
    int*      wcnt2 = wcnt + NPART * NW;                  // 8*MAXNSUB*NW2
    int*      tot2  = wcnt2 + NPART * MAXNSUB * NW2;      // 8*MAXNSUB
    unsigned* bkt   = (unsigned*)(tot2 + NPART * MAXNSUB);// n_edges
    unsigned* bkt2  = bkt + n_edges;                      // nps*CAP (9.6 MB)

    const int ntiles = (n_nodes + 63) / 64;

    k_proj_bcount<<<PROJ_BLOCKS + BKT_BLOCKS, 256, 0, stream>>>(
        x, w_in, b_in, w, a, zb, s1, s2, dst, wcnt,
        n_nodes, ntiles, n_edges, part_sz);

    k_wtot<<<NPART, 256, 0, stream>>>(wcnt, tot8, NW);
    k_wscan<<<NPART, 256, 0, stream>>>(wcnt, tot8, off8, NW);
    k_bwrite<<<BKT_BLOCKS, 256, 0, stream>>>(src, dst, wcnt, bkt, n_edges, part_sz);

    k_scount<<<L2_BLOCKS, 256, 0, stream>>>(bkt, tot8, off8, wcnt2, nsub);
    k_sscan<<<nps, NW2, 0, stream>>>(wcnt2, tot2);
    k_swrite<<<L2_BLOCKS, 256, 0, stream>>>(bkt, tot8, off8, wcnt2, bkt2, nsub);

    k_sorted_agg<<<nps, 512, 0, stream>>>(bkt2, tot2, s1, s2, zb,
                                          h, n_nodes, part_sz, nsub);
}

// Round 19
// 113.512 us; speedup vs baseline: 1.1277x; 1.0084x over previous
//
#include <hip/hip_runtime.h>
#include <hip/hip_bf16.h>

#define IN_DIM 128
#define HID    64
#define OUTD   64
#define NPART  8
#define SUBW   64            // nodes per level-2 window (power of 2)
#define CAP    1536          // fixed sorted-edge slot per (p,sub); mean 1020 sigma 32
#define MAXNSUB 200
#define NW2    128           // level-2 waves per partition
#define PROJ_BLOCKS 1043
#define BKT_BLOCKS 1024      // level-1 radix: NW = 4096 waves
#define L2_BLOCKS 256        // 32 blocks/partition * 4 waves = NW2

typedef __attribute__((ext_vector_type(8))) short bf16x8;
typedef __attribute__((ext_vector_type(4))) float f32x4;

__device__ __forceinline__ float gelu_exact(float v) {
    return v * 0.5f * (1.0f + erff(v * 0.70710678118654752f));
}
__device__ __forceinline__ short f2bf(float f) {
    __hip_bfloat16 b = __float2bfloat16(f);   // RNE
    return *reinterpret_cast<short*>(&b);
}
__device__ __forceinline__ float bf2f(ushort u) {
    return __uint_as_float(((unsigned)u) << 16);
}

// ---------------------------------------------------------------------------
// FUSED K1: blocks [0,PROJ_BLOCKS) = MFMA node projection; rest = level-1
// count (ballot, no atomics). Independent -> concurrent. (R17-proven)
// ---------------------------------------------------------------------------
__global__ __launch_bounds__(256) void k_proj_bcount(
    const float* __restrict__ x, const float* __restrict__ w_in,
    const float* __restrict__ b_in, const float* __restrict__ w,
    const float* __restrict__ a,
    ushort* __restrict__ zb, float* __restrict__ s1, float* __restrict__ s2,
    const int* __restrict__ dst, int* __restrict__ wcnt,
    int n_nodes, int ntiles, int n_edges, int part_sz)
{
    __shared__ ushort h0s[4][16 * 64];

    const int tid = threadIdx.x;

    if (blockIdx.x < PROJ_BLOCKS) {
        const int wv = tid >> 6, l = tid & 63;
        const int c = l & 15, g = l >> 4;

        bf16x8 B1[4][4];
        #pragma unroll
        for (int s = 0; s < 4; ++s)
            #pragma unroll
            for (int t = 0; t < 4; ++t) {
                bf16x8 f;
                #pragma unroll
                for (int e = 0; e < 8; ++e)
                    f[e] = f2bf(w_in[(s * 32 + g * 8 + e) * HID + t * 16 + c]);
                B1[s][t] = f;
            }
        bf16x8 B2[2][4];
        #pragma unroll
        for (int s = 0; s < 2; ++s)
            #pragma unroll
            for (int t = 0; t < 4; ++t) {
                bf16x8 f;
                #pragma unroll
                for (int e = 0; e < 8; ++e)
                    f[e] = f2bf(w[(s * 32 + g * 8 + e) * OUTD + t * 16 + c]);
                B2[s][t] = f;
            }
        float bias[4], a1c[4], a2c[4];
        #pragma unroll
        for (int t = 0; t < 4; ++t) {
            bias[t] = b_in[t * 16 + c];
            a1c[t]  = a[t * 16 + c];
            a2c[t]  = a[OUTD + t * 16 + c];
        }

        ushort* hrow = &h0s[wv][0];

        for (int tile = blockIdx.x; tile < ntiles; tile += PROJ_BLOCKS) {
            const int nbase = tile * 64 + wv * 16;

            const int row = min(nbase + c, n_nodes - 1);
            const float* xp = x + (size_t)row * IN_DIM;
            bf16x8 A1[4];
            #pragma unroll
            for (int s = 0; s < 4; ++s) {
                const float4 u0 = *(const float4*)(xp + s * 32 + g * 8);
                const float4 u1 = *(const float4*)(xp + s * 32 + g * 8 + 4);
                bf16x8 f;
                f[0] = f2bf(u0.x); f[1] = f2bf(u0.y); f[2] = f2bf(u0.z); f[3] = f2bf(u0.w);
                f[4] = f2bf(u1.x); f[5] = f2bf(u1.y); f[6] = f2bf(u1.z); f[7] = f2bf(u1.w);
                A1[s] = f;
            }

            #pragma unroll
            for (int t = 0; t < 4; ++t) {
                f32x4 acc = {0.f, 0.f, 0.f, 0.f};
                #pragma unroll
                for (int s = 0; s < 4; ++s)
                    acc = __builtin_amdgcn_mfma_f32_16x16x32_bf16(A1[s], B1[s][t], acc, 0, 0, 0);
                #pragma unroll
                for (int r = 0; r < 4; ++r) {
                    const int m = g * 4 + r;
                    const int n = t * 16 + c;
                    const float h0 = gelu_exact(acc[r] + bias[t]);
                    hrow[m * 64 + (n ^ ((m & 7) << 3))] = (ushort)f2bf(h0);
                }
            }
            __syncthreads();

            bf16x8 A2[2];
            #pragma unroll
            for (int s = 0; s < 2; ++s) {
                const int k = s * 32 + g * 8;
                A2[s] = *(const bf16x8*)(hrow + c * 64 + (k ^ ((c & 7) << 3)));
            }

            f32x4 C2[4];
            #pragma unroll
            for (int t = 0; t < 4; ++t) {
                f32x4 acc = {0.f, 0.f, 0.f, 0.f};
                acc = __builtin_amdgcn_mfma_f32_16x16x32_bf16(A2[0], B2[0][t], acc, 0, 0, 0);
                acc = __builtin_amdgcn_mfma_f32_16x16x32_bf16(A2[1], B2[1][t], acc, 0, 0, 0);
                C2[t] = acc;
            }

            float p1v[4] = {0.f, 0.f, 0.f, 0.f}, p2v[4] = {0.f, 0.f, 0.f, 0.f};
            #pragma unroll
            for (int t = 0; t < 4; ++t)
                #pragma unroll
                for (int r = 0; r < 4; ++r) {
                    p1v[r] = fmaf(C2[t][r], a1c[t], p1v[r]);
                    p2v[r] = fmaf(C2[t][r], a2c[t], p2v[r]);
                    const int node = nbase + g * 4 + r;
                    if (node < n_nodes)
                        zb[(size_t)node * OUTD + t * 16 + c] = (ushort)f2bf(C2[t][r]);
                }

            #pragma unroll
            for (int r = 0; r < 4; ++r) {
                p1v[r] += __shfl_xor(p1v[r], 1, 64);
                p1v[r] += __shfl_xor(p1v[r], 2, 64);
                p1v[r] += __shfl_xor(p1v[r], 4, 64);
                p1v[r] += __shfl_xor(p1v[r], 8, 64);
                p2v[r] += __shfl_xor(p2v[r], 1, 64);
                p2v[r] += __shfl_xor(p2v[r], 2, 64);
                p2v[r] += __shfl_xor(p2v[r], 4, 64);
                p2v[r] += __shfl_xor(p2v[r], 8, 64);
            }
            const float v1 = (c == 0) ? p1v[0] : (c == 1) ? p1v[1] : (c == 2) ? p1v[2] : p1v[3];
            const float v2 = (c == 0) ? p2v[0] : (c == 1) ? p2v[1] : (c == 2) ? p2v[2] : p2v[3];
            const int snode = nbase + g * 4 + c;
            if (c < 4 && snode < n_nodes) { s1[snode] = v1; s2[snode] = v2; }
            __syncthreads();
        }
    } else {
        const int bid = blockIdx.x - PROJ_BLOCKS;
        const int lane = tid & 63;
        const int gw = (bid * 256 + tid) >> 6;
        const int nw = (BKT_BLOCKS * 256) >> 6;

        int cnt[NPART];
        #pragma unroll
        for (int p = 0; p < NPART; ++p) cnt[p] = 0;

        const int tiles = (n_edges + 255) >> 8;
        for (int t = gw; t < tiles; t += nw) {
            const int base = (t << 8) + (lane << 2);
            int p0 = -1, p1 = -1, p2 = -1, p3 = -1;
            if (base + 3 < n_edges) {
                const int4 d4 = *(const int4*)(dst + base);
                p0 = d4.x / part_sz; p1 = d4.y / part_sz;
                p2 = d4.z / part_sz; p3 = d4.w / part_sz;
            } else {
                if (base + 0 < n_edges) p0 = dst[base + 0] / part_sz;
                if (base + 1 < n_edges) p1 = dst[base + 1] / part_sz;
                if (base + 2 < n_edges) p2 = dst[base + 2] / part_sz;
                if (base + 3 < n_edges) p3 = dst[base + 3] / part_sz;
            }
            #pragma unroll
            for (int pp = 0; pp < NPART; ++pp) {
                cnt[pp] += __popcll(__ballot(p0 == pp)) + __popcll(__ballot(p1 == pp))
                         + __popcll(__ballot(p2 == pp)) + __popcll(__ballot(p3 == pp));
            }
        }
        if (lane == 0) {
            #pragma unroll
            for (int pp = 0; pp < NPART; ++pp) wcnt[pp * nw + gw] = cnt[pp];
        }
    }
}

// ---------------------------------------------------------------------------
// Level-1 scans, hierarchical + segmented (R14/R17-proven).
// ---------------------------------------------------------------------------
__global__ __launch_bounds__(256) void k_wtot(
    const int* __restrict__ wcnt, int* __restrict__ tot8, int nw)
{
    __shared__ int buf[256];
    const int p = blockIdx.x, tid = threadIdx.x;
    const int seg = (nw + 255) >> 8;
    const int s0 = tid * seg, s1e = min(s0 + seg, nw);
    int s = 0;
    for (int i = s0; i < s1e; ++i) s += wcnt[p * nw + i];
    buf[tid] = s;
    __syncthreads();
    #pragma unroll
    for (int off = 128; off; off >>= 1) {
        if (tid < off) buf[tid] += buf[tid + off];
        __syncthreads();
    }
    if (tid == 0) tot8[p] = buf[0];
}

__global__ __launch_bounds__(256) void k_wscan(
    int* __restrict__ wcnt, const int* __restrict__ tot8,
    int* __restrict__ off8, int nw)
{
    __shared__ int buf[256];
    const int p = blockIdx.x, tid = threadIdx.x;
    int running = 0;
    for (int q = 0; q < p; ++q) running += tot8[q];
    if (tid == 0) off8[p] = running;

    const int seg = (nw + 255) >> 8;
    const int s0 = tid * seg, s1e = min(s0 + seg, nw);
    int tsum = 0;
    for (int i = s0; i < s1e; ++i) tsum += wcnt[p * nw + i];
    buf[tid] = tsum;
    __syncthreads();
    #pragma unroll
    for (int off = 1; off < 256; off <<= 1) {
        int t = (tid >= off) ? buf[tid - off] : 0;
        __syncthreads();
        buf[tid] += t;
        __syncthreads();
    }
    int prefix = running + buf[tid] - tsum;
    for (int i = s0; i < s1e; ++i) {
        const int v = wcnt[p * nw + i];
        wcnt[p * nw + i] = prefix;
        prefix += v;
    }
}

__global__ __launch_bounds__(256) void k_bwrite(
    const int* __restrict__ src, const int* __restrict__ dst,
    const int* __restrict__ wbase, unsigned* __restrict__ bkt,
    int n_edges, int part_sz)
{
    const int lane = threadIdx.x & 63;
    const int gw = (blockIdx.x * 256 + threadIdx.x) >> 6;
    const int nw = (gridDim.x * 256) >> 6;
    const unsigned long long below = (lane == 63) ? 0x7FFFFFFFFFFFFFFFull
                                                  : ((1ull << lane) - 1ull);

    int base8[NPART];
    #pragma unroll
    for (int pp = 0; pp < NPART; ++pp) base8[pp] = wbase[pp * nw + gw];

    const int tiles = (n_edges + 255) >> 8;
    for (int t = gw; t < tiles; t += nw) {
        const int base = (t << 8) + (lane << 2);
        int p[4]; unsigned pk[4];
        if (base + 3 < n_edges) {
            const int4 d4 = *(const int4*)(dst + base);
            const int4 s4 = *(const int4*)(src + base);
            p[0] = d4.x / part_sz; pk[0] = ((unsigned)(d4.x - p[0] * part_sz) << 17) | (unsigned)s4.x;
            p[1] = d4.y / part_sz; pk[1] = ((unsigned)(d4.y - p[1] * part_sz) << 17) | (unsigned)s4.y;
            p[2] = d4.z / part_sz; pk[2] = ((unsigned)(d4.z - p[2] * part_sz) << 17) | (unsigned)s4.z;
            p[3] = d4.w / part_sz; pk[3] = ((unsigned)(d4.w - p[3] * part_sz) << 17) | (unsigned)s4.w;
        } else {
            #pragma unroll
            for (int j = 0; j < 4; ++j) {
                if (base + j < n_edges) {
                    const int d = dst[base + j];
                    p[j] = d / part_sz;
                    pk[j] = ((unsigned)(d - p[j] * part_sz) << 17) | (unsigned)src[base + j];
                } else p[j] = -1;
            }
        }
        #pragma unroll
        for (int pp = 0; pp < NPART; ++pp) {
            const unsigned long long m0 = __ballot(p[0] == pp);
            const unsigned long long m1 = __ballot(p[1] == pp);
            const unsigned long long m2 = __ballot(p[2] == pp);
            const unsigned long long m3 = __ballot(p[3] == pp);
            const int k0 = __popcll(m0), k1 = __popcll(m1);
            const int k2 = __popcll(m2), k3 = __popcll(m3);
            const int go = base8[pp];
            if ((m0 >> lane) & 1) bkt[go + __popcll(m0 & below)] = pk[0];
            if ((m1 >> lane) & 1) bkt[go + k0 + __popcll(m1 & below)] = pk[1];
            if ((m2 >> lane) & 1) bkt[go + k0 + k1 + __popcll(m2 & below)] = pk[2];
            if ((m3 >> lane) & 1) bkt[go + k0 + k1 + k2 + __popcll(m3 & below)] = pk[3];
            base8[pp] = go + k0 + k1 + k2 + k3;
        }
    }
}

// ---------------------------------------------------------------------------
// LEVEL-2: sub-bucket split; sub = pk>>23 (dst_local>>6): 64-node windows.
// NW2=128 waves/partition; static-CAP bkt2 slots. (R18-proven)
// ---------------------------------------------------------------------------
__global__ __launch_bounds__(256) void k_scount(
    const unsigned* __restrict__ bkt, const int* __restrict__ tot8,
    const int* __restrict__ off8, int* __restrict__ wcnt2, int nsub)
{
    __shared__ int lcnt[4][MAXNSUB];
    const int p = blockIdx.x & (NPART - 1);
    const int wv = threadIdx.x >> 6, lane = threadIdx.x & 63;
    const int w2 = (blockIdx.x >> 3) * 4 + wv;          // 0..NW2-1

    for (int i = lane; i < nsub; i += 64) lcnt[wv][i] = 0;

    const int nB = tot8[p];
    const unsigned* b = bkt + off8[p];
    const int nt = (nB + 255) >> 8;
    for (int t = w2; t < nt; t += NW2) {
        const int base = (t << 8) + (lane << 2);
        if (base + 3 < nB) {
            const uint4 v = *(const uint4*)(b + base);
            atomicAdd(&lcnt[wv][v.x >> 23], 1);
            atomicAdd(&lcnt[wv][v.y >> 23], 1);
            atomicAdd(&lcnt[wv][v.z >> 23], 1);
            atomicAdd(&lcnt[wv][v.w >> 23], 1);
        } else {
            for (int j = 0; j < 4; ++j)
                if (base + j < nB) atomicAdd(&lcnt[wv][b[base + j] >> 23], 1);
        }
    }
    for (int i = lane; i < nsub; i += 64)
        wcnt2[(p * nsub + i) * NW2 + w2] = lcnt[wv][i];
}

__global__ __launch_bounds__(128) void k_sscan(
    int* __restrict__ wcnt2, int* __restrict__ tot2)
{
    __shared__ int buf[NW2];
    const int ps = blockIdx.x, tid = threadIdx.x;
    const int v = wcnt2[ps * NW2 + tid];
    buf[tid] = v;
    __syncthreads();
    #pragma unroll
    for (int off = 1; off < NW2; off <<= 1) {
        int t = (tid >= off) ? buf[tid - off] : 0;
        __syncthreads();
        buf[tid] += t;
        __syncthreads();
    }
    wcnt2[ps * NW2 + tid] = buf[tid] - v;   // exclusive within sub-bucket
    if (tid == NW2 - 1) tot2[ps] = buf[NW2 - 1];
}

__global__ __launch_bounds__(256) void k_swrite(
    const unsigned* __restrict__ bkt, const int* __restrict__ tot8,
    const int* __restrict__ off8, const int* __restrict__ wcnt2,
    unsigned* __restrict__ bkt2, int nsub)
{
    __shared__ int lbase[4][MAXNSUB];
    const int p = blockIdx.x & (NPART - 1);
    const int wv = threadIdx.x >> 6, lane = threadIdx.x & 63;
    const int w2 = (blockIdx.x >> 3) * 4 + wv;

    for (int i = lane; i < nsub; i += 64)
        lbase[wv][i] = (p * nsub + i) * CAP + wcnt2[(p * nsub + i) * NW2 + w2];

    const int nB = tot8[p];
    const unsigned* b = bkt + off8[p];
    const int nt = (nB + 255) >> 8;
    for (int t = w2; t < nt; t += NW2) {
        const int base = (t << 8) + (lane << 2);
        if (base + 3 < nB) {
            const uint4 v = *(const uint4*)(b + base);
            bkt2[atomicAdd(&lbase[wv][v.x >> 23], 1)] = v.x;
            bkt2[atomicAdd(&lbase[wv][v.y >> 23], 1)] = v.y;
            bkt2[atomicAdd(&lbase[wv][v.z >> 23], 1)] = v.z;
            bkt2[atomicAdd(&lbase[wv][v.w >> 23], 1)] = v.w;
        } else {
            for (int j = 0; j < 4; ++j)
                if (base + j < nB) {
                    const unsigned pk = b[base + j];
                    bkt2[atomicAdd(&lbase[wv][pk >> 23], 1)] = pk;
                }
        }
    }
}

// ---------------------------------------------------------------------------
// SORTED AGG v5: as R18 (SUBW=64, 512 threads, q precomputed, unroll-8,
// register racc/rden) but the 64-wide counter scan is done by WAVE 0 via
// __shfl_up (6 steps, no internal barriers) — replaces ~14 __syncthreads
// with 1. R18 counters showed occ 55% with full residency: barrier stall.
// ---------------------------------------------------------------------------
__global__ __launch_bounds__(512) void k_sorted_agg(
    const unsigned* __restrict__ bkt2, const int* __restrict__ tot2,
    const float* __restrict__ s1, const float* __restrict__ s2,
    const ushort* __restrict__ zb, float* __restrict__ h,
    int n_nodes, int part_sz, int nsub)
{
    __shared__ uint2 sorted[CAP];      // 12 KB
    __shared__ int cnt[SUBW];
    __shared__ int scn[SUBW];
    __shared__ int cur[SUBW];

    const int p = blockIdx.x & (NPART - 1);
    const int sub = blockIdx.x >> 3;
    const int ps = p * nsub + sub;
    const int pbase = p * part_sz;
    const int wbase = sub * SUBW;
    const int psz = min(part_sz, n_nodes - pbase);
    const int wn = min(SUBW, psz - wbase);
    if (wn <= 0) return;

    const int tid = threadIdx.x, wv = tid >> 6, lane = tid & 63;

    if (tid < SUBW) cnt[tid] = 0;
    __syncthreads();

    int n2 = tot2[ps];
    if (n2 > CAP) n2 = CAP;   // defensive; mean 1020, sigma 32
    const unsigned* b = bkt2 + (size_t)ps * CAP;

    // pass 1: histogram by window-local dst
    for (int i = tid; i < n2; i += 512)
        atomicAdd(&cnt[(b[i] >> 17) & (SUBW - 1)], 1);
    __syncthreads();

    // wave-0 shfl inclusive scan over 64 counters (no internal barriers)
    if (wv == 0) {
        const int c0 = cnt[lane];
        int v = c0;
        #pragma unroll
        for (int off = 1; off < 64; off <<= 1) {
            const int t = __shfl_up(v, off, 64);
            if (lane >= off) v += t;
        }
        scn[lane] = v;
        cur[lane] = v - c0;
    }
    __syncthreads();

    // pass 2: scatter dst-sorted + lane-parallel q precompute
    for (int i = tid; i < n2; i += 512) {
        const unsigned pk = b[i];
        const int sv = (int)(pk & 0x1FFFFu);
        const int dfull = (int)(pk >> 17);
        float e = s1[sv] + s2[pbase + dfull];
        e = e > 0.f ? e : 0.01f * e;
        const float q = __expf(e);
        const int pos = atomicAdd(&cur[dfull & (SUBW - 1)], 1);
        sorted[pos] = make_uint2(pk, __float_as_uint(q));
    }
    __syncthreads();

    // wave wv owns window-local nodes [nlo, nhi): 8 nodes per wave
    const int nlo = wv * 8;
    const int nhi = nlo + 8;
    const int lo = (nlo == 0) ? 0 : scn[nlo - 1];
    const int hi = scn[nhi - 1];

    float* __restrict__ hb = h + (size_t)(pbase + wbase) * OUTD + lane;

    float racc = 0.f, rden = 0.f;
    int curd = -1;
    int lastw = nlo - 1;

#define FLUSH() do { if (curd >= 0) { \
        for (int z_ = lastw + 1; z_ < curd; ++z_) hb[(size_t)z_ * OUTD] = 0.f; \
        hb[(size_t)curd * OUTD] = racc / fmaxf(rden, 1e-9f); \
        lastw = curd; } } while (0)

#define STEP2(D, Q, Z) do { \
        if ((D) != curd) { FLUSH(); curd = (D); racc = 0.f; rden = 0.f; } \
        racc = fmaf((Q), (Z), racc); rden += (Q); } while (0)

    int e = lo;
    for (; e + 7 < hi; e += 8) {
        const uint2 u0 = sorted[e + 0], u1 = sorted[e + 1];
        const uint2 u2 = sorted[e + 2], u3 = sorted[e + 3];
        const uint2 u4 = sorted[e + 4], u5 = sorted[e + 5];
        const uint2 u6 = sorted[e + 6], u7 = sorted[e + 7];
        const float z0 = bf2f(zb[(size_t)(u0.x & 0x1FFFFu) * OUTD + lane]);
        const float z1 = bf2f(zb[(size_t)(u1.x & 0x1FFFFu) * OUTD + lane]);
        const float z2 = bf2f(zb[(size_t)(u2.x & 0x1FFFFu) * OUTD + lane]);
        const float z3 = bf2f(zb[(size_t)(u3.x & 0x1FFFFu) * OUTD + lane]);
        const float z4 = bf2f(zb[(size_t)(u4.x & 0x1FFFFu) * OUTD + lane]);
        const float z5 = bf2f(zb[(size_t)(u5.x & 0x1FFFFu) * OUTD + lane]);
        const float z6 = bf2f(zb[(size_t)(u6.x & 0x1FFFFu) * OUTD + lane]);
        const float z7 = bf2f(zb[(size_t)(u7.x & 0x1FFFFu) * OUTD + lane]);
        STEP2((int)((u0.x >> 17) & (SUBW - 1)), __uint_as_float(u0.y), z0);
        STEP2((int)((u1.x >> 17) & (SUBW - 1)), __uint_as_float(u1.y), z1);
        STEP2((int)((u2.x >> 17) & (SUBW - 1)), __uint_as_float(u2.y), z2);
        STEP2((int)((u3.x >> 17) & (SUBW - 1)), __uint_as_float(u3.y), z3);
        STEP2((int)((u4.x >> 17) & (SUBW - 1)), __uint_as_float(u4.y), z4);
        STEP2((int)((u5.x >> 17) & (SUBW - 1)), __uint_as_float(u5.y), z5);
        STEP2((int)((u6.x >> 17) & (SUBW - 1)), __uint_as_float(u6.y), z6);
        STEP2((int)((u7.x >> 17) & (SUBW - 1)), __uint_as_float(u7.y), z7);
    }
    for (; e < hi; ++e) {
        const uint2 u = sorted[e];
        const float z = bf2f(zb[(size_t)(u.x & 0x1FFFFu) * OUTD + lane]);
        STEP2((int)((u.x >> 17) & (SUBW - 1)), __uint_as_float(u.y), z);
    }
    FLUSH();
    const int zend = min(nhi, wn);
    for (int z = lastw + 1; z < zend; ++z)
        hb[(size_t)z * OUTD] = 0.f;
#undef STEP2
#undef FLUSH
}

extern "C" void kernel_launch(void* const* d_in, const int* in_sizes, int n_in,
                              void* d_out, int out_size, void* d_ws, size_t ws_size,
                              hipStream_t stream)
{
    const float* x    = (const float*)d_in[0];
    const float* w_in = (const float*)d_in[1];
    const float* b_in = (const float*)d_in[2];
    const float* w    = (const float*)d_in[3];
    const float* a    = (const float*)d_in[4];
    const int*   src  = (const int*)d_in[5];
    const int*   dst  = (const int*)d_in[6];
    const int n_nodes = in_sizes[0] / IN_DIM;
    const int n_edges = in_sizes[5];

    float* h = (float*)d_out;

    const int NW = BKT_BLOCKS * 4;
    const int part_sz = (n_nodes + NPART - 1) / NPART;
    const int nsub = (part_sz + SUBW - 1) / SUBW;  // 196 <= MAXNSUB
    const int nps = NPART * nsub;

    // workspace (~30 MB): zb | s1 | s2 | tot8/off8 | wcnt | wcnt2 | tot2 | bkt | bkt2
    ushort*   zb    = (ushort*)d_ws;                      // n_nodes*64 bf16
    float*    s1    = (float*)(zb + (size_t)n_nodes * OUTD);
    float*    s2    = s1 + n_nodes;
    int*      tot8  = (int*)(s2 + n_nodes);               // 8
    int*      off8  = tot8 + NPART;                       // 9 (region padded to 64)
    int*      wcnt  = tot8 + 64;                          // 8*NW
    int*      wcnt2 = wcnt + NPART * NW;                  // 8*MAXNSUB*NW2
    int*      tot2  = wcnt2 + NPART * MAXNSUB * NW2;      // 8*MAXNSUB
    unsigned* bkt   = (unsigned*)(tot2 + NPART * MAXNSUB);// n_edges
    unsigned* bkt2  = bkt + n_edges;                      // nps*CAP (9.6 MB)

    const int ntiles = (n_nodes + 63) / 64;

    k_proj_bcount<<<PROJ_BLOCKS + BKT_BLOCKS, 256, 0, stream>>>(
        x, w_in, b_in, w, a, zb, s1, s2, dst, wcnt,
        n_nodes, ntiles, n_edges, part_sz);

    k_wtot<<<NPART, 256, 0, stream>>>(wcnt, tot8, NW);
    k_wscan<<<NPART, 256, 0, stream>>>(wcnt, tot8, off8, NW);
    k_bwrite<<<BKT_BLOCKS, 256, 0, stream>>>(src, dst, wcnt, bkt, n_edges, part_sz);

    k_scount<<<L2_BLOCKS, 256, 0, stream>>>(bkt, tot8, off8, wcnt2, nsub);
    k_sscan<<<nps, NW2, 0, stream>>>(wcnt2, tot2);
    k_swrite<<<L2_BLOCKS, 256, 0, stream>>>(bkt, tot8, off8, wcnt2, bkt2, nsub);

    k_sorted_agg<<<nps, 512, 0, stream>>>(bkt2, tot2, s1, s2, zb,
                                          h, n_nodes, part_sz, nsub);
}